// Round 2
// baseline (6363.595 us; speedup 1.0000x reference)
//
#include <hip/hip_runtime.h>
#include <hip/hip_bf16.h>
#include <math.h>

// Problem constants
#define NTOK 1024          // Hp*Wp = 32*32
#define CDIM 768
#define BDIM 2
#define ROWS (BDIM*NTOK)   // 2048
#define NHEAD 12
#define HEADD 64
#define SCALE 0.125f       // 64^-0.5

typedef __attribute__((ext_vector_type(8))) __bf16 bfx8;
typedef __attribute__((ext_vector_type(4))) float f32x4;

__device__ __forceinline__ float us2f(unsigned short u) {
  return __uint_as_float(((unsigned int)u) << 16);
}
// dtype-flexible scalar load at ELEMENT index i: isbf ? bf16[i] : f32[i]
__device__ __forceinline__ float ldP(const void* p, size_t i, bool isbf) {
  return isbf ? us2f(((const unsigned short*)p)[i]) : ((const float*)p)[i];
}
__device__ __forceinline__ float4 ldP4(const void* p, size_t i, bool isbf) {
  if (isbf) {
    ushort4 u = *(const ushort4*)((const unsigned short*)p + i);
    return make_float4(us2f(u.x), us2f(u.y), us2f(u.z), us2f(u.w));
  }
  return *(const float4*)((const float*)p + i);
}

__device__ __forceinline__ float waveSum(float v) {
#pragma unroll
  for (int off = 32; off; off >>= 1) v += __shfl_xor(v, off, 64);
  return v;
}

// ---------------------------------------------------------------- dtype detector
// bf16 buffer of 0.02-scale gaussians: ~256/256 halfwords have sane exponent.
// f32 buffer: only odd halfwords do (~152/256 expected). Threshold 220 (≈15σ).
__global__ void detect_kernel(const void* __restrict__ probe, int* __restrict__ flag) {
  const unsigned short* u = (const unsigned short*)probe;
  int plaus = 0;
  for (int i = 0; i < 256; i++) {
    int e = (u[i] >> 7) & 0xFF;
    if (e >= 0x60 && e <= 0x8F) plaus++;
  }
  *flag = (plaus >= 220) ? 1 : 0;
}

// ---------------------------------------------------------------- im2col
__global__ __launch_bounds__(256) void im2col_kernel(const void* __restrict__ x,
                                                     float* __restrict__ col,
                                                     const int* __restrict__ dt) {
  bool isbf = (*dt != 0);
  int idx = blockIdx.x * 256 + threadIdx.x;     // < 2048*768
  int k = idx % 768;
  int row = idx / 768;
  int n = row & (NTOK - 1);
  int b = row >> 10;
  int ci = k >> 8;
  int rem = k & 255;
  int py = rem >> 4, px = rem & 15;
  int hp = n >> 5, wp = n & 31;
  int iy = hp * 16 + py, ix = wp * 16 + px;
  size_t xi = (((size_t)(b * 3 + ci) * 512) + iy) * 512 + ix;
  col[idx] = ldP(x, xi, isbf);
}

// ---------------------------------------------------------------- GEMM
// Y[m,n](ldy) (+)= A[m,k](lda, f32) @ W[wOff + n, k]^T + bias[bOff + n]
// flags: bit0 residual add, bit1 exact GELU
// bf16-weight path: MFMA 16x16x32_bf16 with split-A (hi+lo) for ~17-bit mantissa.
// f32-weight path: original scalar-VALU version (bitwise-identical behavior).
__global__ __launch_bounds__(256) void gemm_kernel(
    const float* __restrict__ A, int lda,
    const void* __restrict__ W, size_t wOff,
    const void* __restrict__ bias, size_t bOff,
    float* __restrict__ Y, int ldy,
    int Nout, int K, int flags, const int* __restrict__ dt) {
  bool isbf = (*dt != 0);
  union SM {
    struct { float As[16][64]; float Ws[16][64]; } sc;                // 8 KB
    struct { __bf16 Ah[64 * 40]; __bf16 Al[64 * 40]; __bf16 Wb[64 * 40]; } mf; // 15360 B
  };
  __shared__ SM sm;
  int tid = threadIdx.x;
  int mbase = blockIdx.y * 64;
  int nbase = blockIdx.x * 64;

  if (isbf) {
    // ---------------- MFMA path ----------------
    const int ROWP = 40;                 // padded LDS row (shorts); 80B = 16B-aligned frag reads
    int wid = tid >> 6;                  // wave 0..3, owns rows [wid*16, wid*16+16)
    int lane = tid & 63;
    int lr = lane & 15;                  // fragment row/col lane index
    int lg = lane >> 4;                  // k-group 0..3
    int srow = tid >> 2;                 // staging row 0..63
    int sk8 = (tid & 3) << 3;            // staging k offset 0,8,16,24
    int gn = nbase + srow;

    f32x4 acc[4];
#pragma unroll
    for (int j = 0; j < 4; j++) acc[j] = f32x4{0.f, 0.f, 0.f, 0.f};

    const float* aRow = A + (size_t)(mbase + srow) * lda;
    const __bf16* Wp = (const __bf16*)W + wOff + (size_t)gn * K;
    bool wok = (gn < Nout);

    for (int k0 = 0; k0 < K; k0 += 32) {
      // stage A (f32 -> bf16 hi + lo)
      float4 a0 = *(const float4*)(aRow + k0 + sk8);
      float4 a1 = *(const float4*)(aRow + k0 + sk8 + 4);
      float av[8] = {a0.x, a0.y, a0.z, a0.w, a1.x, a1.y, a1.z, a1.w};
      bfx8 h8, l8;
#pragma unroll
      for (int i = 0; i < 8; i++) {
        __bf16 h = (__bf16)av[i];
        h8[i] = h;
        l8[i] = (__bf16)(av[i] - (float)h);
      }
      *(bfx8*)&sm.mf.Ah[srow * ROWP + sk8] = h8;
      *(bfx8*)&sm.mf.Al[srow * ROWP + sk8] = l8;
      // stage W (bf16 copy)
      bfx8 wv;
#pragma unroll
      for (int i = 0; i < 8; i++) wv[i] = (__bf16)0.f;
      if (wok) wv = *(const bfx8*)(Wp + k0 + sk8);
      *(bfx8*)&sm.mf.Wb[srow * ROWP + sk8] = wv;
      __syncthreads();

      // fragments: A[m=lr][k=8*lg+j], B[k=8*lg+j][n=lr]
      bfx8 ah = *(const bfx8*)&sm.mf.Ah[(wid * 16 + lr) * ROWP + lg * 8];
      bfx8 al = *(const bfx8*)&sm.mf.Al[(wid * 16 + lr) * ROWP + lg * 8];
#pragma unroll
      for (int j = 0; j < 4; j++) {
        bfx8 bv = *(const bfx8*)&sm.mf.Wb[(j * 16 + lr) * ROWP + lg * 8];
        acc[j] = __builtin_amdgcn_mfma_f32_16x16x32_bf16(ah, bv, acc[j], 0, 0, 0);
        acc[j] = __builtin_amdgcn_mfma_f32_16x16x32_bf16(al, bv, acc[j], 0, 0, 0);
      }
      __syncthreads();
    }

    // epilogue: D[row=(lane>>4)*4+reg][col=lane&15] per 16x16 frag
#pragma unroll
    for (int j = 0; j < 4; j++) {
      int n = nbase + j * 16 + lr;
      if (n < Nout) {
        float bv = bias ? ldP(bias, bOff + n, true) : 0.f;
#pragma unroll
        for (int r = 0; r < 4; r++) {
          int m = mbase + wid * 16 + lg * 4 + r;
          float v = acc[j][r] + bv;
          if (flags & 2) v = 0.5f * v * (1.0f + erff(v * 0.70710678118654752f));
          float* yp = Y + (size_t)m * ldy + n;
          if (flags & 1) v += *yp;
          *yp = v;
        }
      }
    }
  } else {
    // ---------------- scalar fallback (f32 weights) ----------------
    int tx = tid & 15, ty = tid >> 4;
    int am = tid >> 2;               // 0..63
    int ak = (tid & 3) << 2;         // 0,4,8,12
    int gn = nbase + am;

    float acc[4][4];
#pragma unroll
    for (int i = 0; i < 4; i++)
#pragma unroll
      for (int j = 0; j < 4; j++) acc[i][j] = 0.f;

    for (int k0 = 0; k0 < K; k0 += 16) {
      float4 av = *(const float4*)(A + (size_t)(mbase + am) * lda + (k0 + ak));
      sm.sc.As[ak + 0][am] = av.x; sm.sc.As[ak + 1][am] = av.y;
      sm.sc.As[ak + 2][am] = av.z; sm.sc.As[ak + 3][am] = av.w;
      float4 wv = make_float4(0.f, 0.f, 0.f, 0.f);
      if (gn < Nout) wv = *(const float4*)((const float*)W + wOff + (size_t)gn * K + (k0 + ak));
      sm.sc.Ws[ak + 0][am] = wv.x; sm.sc.Ws[ak + 1][am] = wv.y;
      sm.sc.Ws[ak + 2][am] = wv.z; sm.sc.Ws[ak + 3][am] = wv.w;
      __syncthreads();
#pragma unroll
      for (int kk = 0; kk < 16; kk++) {
        float4 a = *(const float4*)&sm.sc.As[kk][ty << 2];
        float4 w = *(const float4*)&sm.sc.Ws[kk][tx << 2];
        acc[0][0] += a.x * w.x; acc[0][1] += a.x * w.y; acc[0][2] += a.x * w.z; acc[0][3] += a.x * w.w;
        acc[1][0] += a.y * w.x; acc[1][1] += a.y * w.y; acc[1][2] += a.y * w.z; acc[1][3] += a.y * w.w;
        acc[2][0] += a.z * w.x; acc[2][1] += a.z * w.y; acc[2][2] += a.z * w.z; acc[2][3] += a.z * w.w;
        acc[3][0] += a.w * w.x; acc[3][1] += a.w * w.y; acc[3][2] += a.w * w.z; acc[3][3] += a.w * w.w;
      }
      __syncthreads();
    }

#pragma unroll
    for (int i = 0; i < 4; i++) {
      int m = mbase + (ty << 2) + i;
#pragma unroll
      for (int j = 0; j < 4; j++) {
        int n = nbase + (tx << 2) + j;
        if (n < Nout) {
          float v = acc[i][j];
          if (bias) v += ldP(bias, bOff + n, false);
          if (flags & 2) v = 0.5f * v * (1.0f + erff(v * 0.70710678118654752f));
          float* yp = Y + (size_t)m * ldy + n;
          if (flags & 1) v += *yp;
          *yp = v;
        }
      }
    }
  }
}

// ---------------------------------------------------------------- LayerNorm
__global__ __launch_bounds__(256) void ln_kernel(const float* __restrict__ X,
                                                 const void* __restrict__ gs,
                                                 const void* __restrict__ gb,
                                                 size_t gOff,
                                                 float* __restrict__ H,
                                                 const int* __restrict__ dt) {
  bool isbf = (*dt != 0);
  int row = blockIdx.x;
  int tid = threadIdx.x;
  const float* xr = X + (size_t)row * CDIM;
  float v0 = xr[tid], v1 = xr[tid + 256], v2 = xr[tid + 512];
  float sum = waveSum(v0 + v1 + v2);
  __shared__ float red[4];
  __shared__ float statMu;
  __shared__ float statRs;
  int wid = tid >> 6, lane = tid & 63;
  if (lane == 0) red[wid] = sum;
  __syncthreads();
  if (tid == 0) statMu = (red[0] + red[1] + red[2] + red[3]) * (1.0f / 768.0f);
  __syncthreads();
  float mu = statMu;
  float d0 = v0 - mu, d1 = v1 - mu, d2 = v2 - mu;
  float sq = waveSum(d0 * d0 + d1 * d1 + d2 * d2);
  if (lane == 0) red[wid] = sq;
  __syncthreads();
  if (tid == 0)
    statRs = rsqrtf((red[0] + red[1] + red[2] + red[3]) * (1.0f / 768.0f) + 1e-6f);
  __syncthreads();
  float rs = statRs;
  float* hr = H + (size_t)row * CDIM;
  hr[tid]       = d0 * rs * ldP(gs, gOff + tid, isbf)       + ldP(gb, gOff + tid, isbf);
  hr[tid + 256] = d1 * rs * ldP(gs, gOff + tid + 256, isbf) + ldP(gb, gOff + tid + 256, isbf);
  hr[tid + 512] = d2 * rs * ldP(gs, gOff + tid + 512, isbf) + ldP(gb, gOff + tid + 512, isbf);
}

// ---------------------------------------------------------------- deformable attention (fused)
__global__ __launch_bounds__(256) void deform_kernel(const float* __restrict__ QKV,
                                                     const float* __restrict__ OFFS,
                                                     float* __restrict__ ATT) {
  int gid = blockIdx.x * 4 + (threadIdx.x >> 6);   // < 24576 = 2048*12
  int lane = threadIdx.x & 63;
  int h = gid % NHEAD;
  int bn = gid / NHEAD;          // b*1024 + n
  int n = bn & (NTOK - 1);
  int b = bn >> 10;
  int hp = n >> 5, wp = n & 31;

  float qd = QKV[(size_t)bn * 2304 + h * HEADD + lane];
  const float* orow = OFFS + (size_t)bn * 96 + h * 8;

  float sv[4], sc[4];
#pragma unroll
  for (int p = 0; p < 4; p++) {
    float ox = orow[p * 2 + 0];
    float oy = orow[p * 2 + 1];
    float xx = (float)wp + ox;     // sample pos in pixel coords (derived)
    float yy = (float)hp + oy;
    float x0f = floorf(xx), y0f = floorf(yy);
    int x0 = (int)x0f, y0 = (int)y0f;
    float wx = xx - x0f, wy = yy - y0f;
    int xs[2] = {x0, x0 + 1};
    int ys[2] = {y0, y0 + 1};
    float wxs[2] = {1.f - wx, wx};
    float wys[2] = {1.f - wy, wy};
    float skv = 0.f, svv = 0.f;
#pragma unroll
    for (int cy = 0; cy < 2; cy++) {
#pragma unroll
      for (int cx = 0; cx < 2; cx++) {
        int yi = ys[cy], xi = xs[cx];
        if (yi >= 0 && yi < 32 && xi >= 0 && xi < 32) {
          const float* kp = QKV + ((size_t)(b * NTOK + (yi << 5) + xi)) * 2304 + CDIM + h * HEADD + lane;
          float w = wys[cy] * wxs[cx];
          skv += w * kp[0];
          svv += w * kp[CDIM];
        }
      }
    }
    sv[p] = svv;
    sc[p] = waveSum(qd * skv) * SCALE;
  }
  float mx = fmaxf(fmaxf(sc[0], sc[1]), fmaxf(sc[2], sc[3]));
  float e0 = expf(sc[0] - mx), e1 = expf(sc[1] - mx), e2 = expf(sc[2] - mx), e3 = expf(sc[3] - mx);
  float l = e0 + e1 + e2 + e3;
  float od = (e0 * sv[0] + e1 * sv[1] + e2 * sv[2] + e3 * sv[3]) / l;
  ATT[(size_t)bn * CDIM + h * HEADD + lane] = od;
}

// ---------------------------------------------------------------- full attention (flash partial + combine)
// Thread = (query, 16-dim chunk). 4-thread groups share a query;
// scores reduced via 2x shfl_xor. q[16]+acc[16] => no spill.
// Grid 768 = 2(b) * 12(h) * 2(kc: 512-key chunks) * 16(qb: 64-query tiles).
__global__ __launch_bounds__(256) void flash_partial(const float* __restrict__ QKV,
                                                     float* __restrict__ PACC,
                                                     float* __restrict__ PM,
                                                     float* __restrict__ PL) {
  int bid = blockIdx.x;                 // ((b*12+h)*2 + kc)*16 + qb
  int qb = bid & 15;
  int kc = (bid >> 4) & 1;
  int bh = bid >> 5;                    // 0..23 = b*12 + h
  int h = bh % NHEAD;
  int b = bh / NHEAD;
  int tid = threadIdx.x;
  int qi = tid >> 2;                    // 0..63 query within tile
  int dc = (tid & 3) << 4;              // 0,16,32,48 dim-chunk base
  int n = qb * 64 + qi;

  const float* base = QKV + (size_t)b * NTOK * 2304;
  float q[16];
  const float* qp = base + (size_t)n * 2304 + h * HEADD + dc;
#pragma unroll
  for (int j = 0; j < 4; j++) {
    float4 t = *(const float4*)(qp + 4 * j);
    q[4 * j] = t.x; q[4 * j + 1] = t.y; q[4 * j + 2] = t.z; q[4 * j + 3] = t.w;
  }
  float acc[16];
#pragma unroll
  for (int j = 0; j < 16; j++) acc[j] = 0.f;
  float mrun = -INFINITY, l = 0.f;

  __shared__ float Ks[64][68];   // +4 pad: staging writes 32-way -> 4-way conflict
  __shared__ float Vs[64][68];

  for (int kt = 0; kt < 8; kt++) {
    int mk = kc * 512 + kt * 64;
    {
      int krow = tid >> 2;
      int d0 = (tid & 3) << 4;
      const float* kp = base + (size_t)(mk + krow) * 2304 + CDIM + h * HEADD + d0;
#pragma unroll
      for (int j = 0; j < 4; j++)
        *(float4*)&Ks[krow][d0 + 4 * j] = *(const float4*)(kp + 4 * j);
      const float* vp = kp + CDIM;
#pragma unroll
      for (int j = 0; j < 4; j++)
        *(float4*)&Vs[krow][d0 + 4 * j] = *(const float4*)(vp + 4 * j);
    }
    __syncthreads();
    for (int m = 0; m < 64; m++) {
      const float* kr = &Ks[m][dc];
      float s0 = 0.f, s1 = 0.f, s2 = 0.f, s3 = 0.f;
#pragma unroll
      for (int j = 0; j < 4; j++) {
        s0 += q[4 * j + 0] * kr[4 * j + 0];
        s1 += q[4 * j + 1] * kr[4 * j + 1];
        s2 += q[4 * j + 2] * kr[4 * j + 2];
        s3 += q[4 * j + 3] * kr[4 * j + 3];
      }
      float s = (s0 + s1) + (s2 + s3);
      s += __shfl_xor(s, 1, 64);        // reduce across the 4-lane dim group
      s += __shfl_xor(s, 2, 64);
      s *= SCALE;
      const float* vr = &Vs[m][dc];
      if (s <= mrun) {                  // common path: no new max, no rescale
        float p = __expf(s - mrun);
        l += p;
#pragma unroll
        for (int j = 0; j < 16; j++) acc[j] = fmaf(p, vr[j], acc[j]);
      } else {                          // rare: new max -> rescale (p == 1)
        float alpha = __expf(mrun - s);
        l = fmaf(l, alpha, 1.f);
#pragma unroll
        for (int j = 0; j < 16; j++) acc[j] = fmaf(acc[j], alpha, vr[j]);
        mrun = s;
      }
    }
    __syncthreads();
  }

  size_t idx = (size_t)(bh * 2 + kc) * NTOK + n;
  if ((tid & 3) == 0) {
    PM[idx] = mrun;
    PL[idx] = l;
  }
  float* ap = PACC + idx * 64 + dc;
#pragma unroll
  for (int j = 0; j < 4; j++) {
    float4 t;
    t.x = acc[4 * j]; t.y = acc[4 * j + 1]; t.z = acc[4 * j + 2]; t.w = acc[4 * j + 3];
    *(float4*)(ap + 4 * j) = t;
  }
}

__global__ __launch_bounds__(256) void flash_combine(const float* __restrict__ PACC,
                                                     const float* __restrict__ PM,
                                                     const float* __restrict__ PL,
                                                     float* __restrict__ ATT) {
  int gid = blockIdx.x * 4 + (threadIdx.x >> 6);   // bh*1024 + n, total 24576
  int lane = threadIdx.x & 63;
  int n = gid & (NTOK - 1);
  int bh = gid >> 10;                               // b*12 + h
  size_t base = (size_t)bh * 2048 + n;              // 2 partials per bh
  float m0 = PM[base], m1 = PM[base + 1024];
  float mx = fmaxf(m0, m1);
  float w0 = __expf(m0 - mx), w1 = __expf(m1 - mx);
  float l = w0 * PL[base] + w1 * PL[base + 1024];
  float a = w0 * PACC[base * 64 + lane] + w1 * PACC[(base + 1024) * 64 + lane];
  int b = bh / NHEAD, h = bh - b * NHEAD;
  ATT[((size_t)(b * NTOK + n)) * CDIM + h * HEADD + lane] = a / l;
}

// ---------------------------------------------------------------- output transpose (B,N,C)->(B,C,N)
__global__ __launch_bounds__(256) void out_kernel(const float* __restrict__ X,
                                                  void* __restrict__ out,
                                                  const int* __restrict__ dt) {
  bool isbf = (*dt != 0);
  int idx = blockIdx.x * 256 + threadIdx.x;   // < 2*768*1024
  int n = idx & (NTOK - 1);
  int rest = idx >> 10;
  int c = rest % CDIM;
  int b = rest / CDIM;
  float v = X[((size_t)(b * NTOK + n)) * CDIM + c];
  if (isbf)
    ((__hip_bfloat16*)out)[idx] = __float2bfloat16(v);
  else
    ((float*)out)[idx] = v;
}

// ---------------------------------------------------------------- launch
extern "C" void kernel_launch(void* const* d_in, const int* in_sizes, int n_in,
                              void* d_out, int out_size, void* d_ws, size_t ws_size,
                              hipStream_t stream) {
  const void* x       = d_in[0];
  const void* patch_w = d_in[1];
  const void* patch_b = d_in[2];
  const void* ln1_s   = d_in[3];
  const void* ln1_b   = d_in[4];
  const void* qkv_w   = d_in[5];
  const void* offs_w  = d_in[6];
  const void* offs_b  = d_in[7];
  const void* proj_w  = d_in[8];
  const void* proj_b  = d_in[9];
  const void* ln2_s   = d_in[10];
  const void* ln2_b   = d_in[11];
  const void* fc1_w   = d_in[12];
  const void* fc1_b   = d_in[13];
  const void* fc2_w   = d_in[14];
  const void* fc2_b   = d_in[15];

  float* W = (float*)d_ws;
  const size_t XSZ = (size_t)ROWS * CDIM;        // 1,572,864
  float* X    = W;                               // residual stream
  float* Hb   = W + XSZ;                         // LN output
  float* ATT  = W + 2 * XSZ;                     // attention output
  float* QKV  = W + 3 * XSZ;                     // 2048 x 2304 (also im2col scratch)
  float* BIG  = W + 3 * XSZ + (size_t)ROWS * 2304;  // 2048 x 3072 (fc1 hidden / flash PACC)
  float* OFFS = BIG + (size_t)ROWS * 3072;       // 2048 x 96 (also flash PM/PL region)
  float* PM = OFFS;
  float* PL = OFFS + 24 * 4 * NTOK;              // 98,304 (only 49,152 used now)
  int* FLAG = (int*)(OFFS + 196608);

  detect_kernel<<<1, 1, 0, stream>>>(qkv_w, FLAG);

  // patch embed: im2col -> GEMM
  im2col_kernel<<<6144, 256, 0, stream>>>(x, QKV, FLAG);
  gemm_kernel<<<dim3(12, 32), 256, 0, stream>>>(QKV, 768, patch_w, 0, patch_b, 0,
                                                X, 768, 768, 768, 0, FLAG);

  for (int i = 0; i < 6; i++) {
    ln_kernel<<<2048, 256, 0, stream>>>(X, ln1_s, ln1_b, (size_t)i * CDIM, Hb, FLAG);
    gemm_kernel<<<dim3(36, 32), 256, 0, stream>>>(Hb, 768, qkv_w, (size_t)i * 2304 * 768,
                                                  nullptr, 0, QKV, 2304, 2304, 768, 0, FLAG);
    if ((i + 1) % 3 != 0) {
      gemm_kernel<<<dim3(2, 32), 256, 0, stream>>>(QKV, 2304, offs_w, (size_t)i * 96 * 768,
                                                   offs_b, (size_t)i * 96, OFFS, 96, 96, 768, 0, FLAG);
      deform_kernel<<<6144, 256, 0, stream>>>(QKV, OFFS, ATT);
    } else {
      flash_partial<<<768, 256, 0, stream>>>(QKV, BIG, PM, PL);
      flash_combine<<<6144, 256, 0, stream>>>(BIG, PM, PL, ATT);
    }
    gemm_kernel<<<dim3(12, 32), 256, 0, stream>>>(ATT, 768, proj_w, (size_t)i * 768 * 768,
                                                  proj_b, (size_t)i * CDIM, X, 768, 768, 768, 1, FLAG);
    ln_kernel<<<2048, 256, 0, stream>>>(X, ln2_s, ln2_b, (size_t)i * CDIM, Hb, FLAG);
    gemm_kernel<<<dim3(48, 32), 256, 0, stream>>>(Hb, 768, fc1_w, (size_t)i * 3072 * 768,
                                                  fc1_b, (size_t)i * 3072, BIG, 3072, 3072, 768, 2, FLAG);
    gemm_kernel<<<dim3(12, 32), 256, 0, stream>>>(BIG, 3072, fc2_w, (size_t)i * 768 * 3072,
                                                  fc2_b, (size_t)i * CDIM, X, 768, 768, 3072, 1, FLAG);
  }

  out_kernel<<<6144, 256, 0, stream>>>(X, d_out, FLAG);
}

// Round 3
// 4488.178 us; speedup vs baseline: 1.4179x; 1.4179x over previous
//
#include <hip/hip_runtime.h>
#include <hip/hip_bf16.h>
#include <math.h>

// Problem constants
#define NTOK 1024          // Hp*Wp = 32*32
#define CDIM 768
#define BDIM 2
#define ROWS (BDIM*NTOK)   // 2048
#define NHEAD 12
#define HEADD 64
#define SCALE 0.125f       // 64^-0.5

typedef __attribute__((ext_vector_type(8))) __bf16 bfx8;
typedef __attribute__((ext_vector_type(4))) float f32x4;
typedef __attribute__((ext_vector_type(8))) unsigned short u16x8;

__device__ __forceinline__ float us2f(unsigned short u) {
  return __uint_as_float(((unsigned int)u) << 16);
}
__device__ __forceinline__ unsigned short f2bfu(float v) {
  union { __bf16 b; unsigned short u; } c; c.b = (__bf16)v; return c.u;
}
// dtype-flexible scalar load at ELEMENT index i: isbf ? bf16[i] : f32[i]
__device__ __forceinline__ float ldP(const void* p, size_t i, bool isbf) {
  return isbf ? us2f(((const unsigned short*)p)[i]) : ((const float*)p)[i];
}

__device__ __forceinline__ float waveSum(float v) {
#pragma unroll
  for (int off = 32; off; off >>= 1) v += __shfl_xor(v, off, 64);
  return v;
}

// dual-format store: bf16 hi/lo planes (isbf) or f32 (else)
__device__ __forceinline__ void stDual(float v, bool isbf, float* f32p, size_t idx,
                                       unsigned short* hp, unsigned short* lp) {
  if (isbf) {
    unsigned short h = f2bfu(v);
    hp[idx] = h;
    lp[idx] = f2bfu(v - us2f(h));
  } else {
    f32p[idx] = v;
  }
}

// ---------------------------------------------------------------- dtype detector
__global__ void detect_kernel(const void* __restrict__ probe, int* __restrict__ flag) {
  const unsigned short* u = (const unsigned short*)probe;
  int plaus = 0;
  for (int i = 0; i < 256; i++) {
    int e = (u[i] >> 7) & 0xFF;
    if (e >= 0x60 && e <= 0x8F) plaus++;
  }
  *flag = (plaus >= 220) ? 1 : 0;
}

// ---------------------------------------------------------------- im2col (dual output)
__global__ __launch_bounds__(256) void im2col_kernel(const void* __restrict__ x,
                                                     float* __restrict__ col,
                                                     const int* __restrict__ dt) {
  bool isbf = (*dt != 0);
  int idx = blockIdx.x * 256 + threadIdx.x;     // < 2048*768
  int k = idx % 768;
  int row = idx / 768;
  int n = row & (NTOK - 1);
  int b = row >> 10;
  int ci = k >> 8;
  int rem = k & 255;
  int py = rem >> 4, px = rem & 15;
  int hp = n >> 5, wp = n & 31;
  int iy = hp * 16 + py, ix = wp * 16 + px;
  size_t xi = (((size_t)(b * 3 + ci) * 512) + iy) * 512 + ix;
  float v = ldP(x, xi, isbf);
  unsigned short* colH = (unsigned short*)col;
  unsigned short* colL = colH + (size_t)ROWS * CDIM;
  stDual(v, isbf, col, idx, colH, colL);
}

// ---------------------------------------------------------------- q columns -> planes (or f32 copy)
__global__ __launch_bounds__(256) void cvtq_kernel(const float* __restrict__ QKV,
                                                   float* __restrict__ Q,
                                                   const int* __restrict__ dt) {
  bool isbf = (*dt != 0);
  int idx = blockIdx.x * 256 + threadIdx.x;     // < 2048*768
  int row = idx / 768, c = idx - row * 768;
  float v = QKV[(size_t)row * 2304 + c];
  unsigned short* qh = (unsigned short*)Q;
  unsigned short* ql = qh + (size_t)ROWS * CDIM;
  stDual(v, isbf, Q, idx, qh, ql);
}

// ---------------------------------------------------------------- GEMM
// Y[m,n](ldy) (+)= A[m,k] @ W[wOff + n, k]^T + bias[bOff + n]
// isbf: A given as bf16 hi/lo planes (AH, AL = AH + ROWS*lda), W bf16 ->
//       MFMA 16x16x32_bf16, split-A for ~17-bit mantissa.
// else: A f32 at lda, W f32 -> original scalar path.
// flags: bit0 residual add, bit1 exact GELU, bit2 dual (plane) output
__global__ __launch_bounds__(256) void gemm_kernel(
    const void* __restrict__ Areg, int lda,
    const void* __restrict__ Wp, size_t wOff,
    const void* __restrict__ bias, size_t bOff,
    void* __restrict__ Yreg, int ldy,
    int Nout, int K, int flags, const int* __restrict__ dt) {
  bool isbf = (*dt != 0);
  __shared__ __align__(16) unsigned char sm[12288];
  int tid = threadIdx.x;
  int nbase = blockIdx.x * 64;
  int mbase = blockIdx.y * 64;

  if (isbf) {
    // ---------------- MFMA path ----------------
    // LDS: Ah[64][32]bf16 @0 (4KB), Al @4096, Wt[64][32] @8192. Linear 64B rows,
    // 16B units XOR-swizzled by (row>>1)&3 (applied at global source + frag read).
    const unsigned short* AH = (const unsigned short*)Areg;
    const unsigned short* AL = AH + (size_t)ROWS * lda;
    const unsigned short* Wg = (const unsigned short*)Wp + wOff;

    int lane = tid & 63, w = tid >> 6;
    int lr = lane & 15, lg = lane >> 4;

    int srow = tid >> 2, su = tid & 3;
    int susw = su ^ ((srow >> 1) & 3);
    size_t aOff = (size_t)(mbase + srow) * lda + susw * 8;
    int wRow = nbase + srow; if (wRow > Nout - 1) wRow = Nout - 1;
    size_t wSrc = (size_t)wRow * K + susw * 8;

    f32x4 acc[4];
#pragma unroll
    for (int i = 0; i < 4; i++) acc[i] = f32x4{0.f, 0.f, 0.f, 0.f};

    // prefetch tile k0=0 into regs
    u16x8 rH = *(const u16x8*)(AH + aOff);
    u16x8 rL = *(const u16x8*)(AL + aOff);
    u16x8 rW = *(const u16x8*)(Wg + wSrc);

    for (int k0 = 0; k0 < K; k0 += 32) {
      __syncthreads();                       // readers of previous tile done
      *(u16x8*)(sm + tid * 16) = rH;         // uniform lane->16B: conflict-free
      *(u16x8*)(sm + 4096 + tid * 16) = rL;
      *(u16x8*)(sm + 8192 + tid * 16) = rW;
      int k1 = k0 + 32;
      if (k1 < K) {                          // issue next tile: hides under compute
        rH = *(const u16x8*)(AH + aOff + k1);
        rL = *(const u16x8*)(AL + aOff + k1);
        rW = *(const u16x8*)(Wg + wSrc + k1);
      }
      __syncthreads();                       // tile visible
      int rm = w * 16 + lr;
      int ub = (lg ^ ((lr >> 1) & 3)) * 16;  // swizzled unit (rows: base mult of 16)
      bfx8 ah = *(const bfx8*)(sm + rm * 64 + ub);
      bfx8 al = *(const bfx8*)(sm + 4096 + rm * 64 + ub);
#pragma unroll
      for (int nf = 0; nf < 4; nf++) {
        int rn = nf * 16 + lr;
        bfx8 bv = *(const bfx8*)(sm + 8192 + rn * 64 + ub);
        acc[nf] = __builtin_amdgcn_mfma_f32_16x16x32_bf16(ah, bv, acc[nf], 0, 0, 0);
        acc[nf] = __builtin_amdgcn_mfma_f32_16x16x32_bf16(al, bv, acc[nf], 0, 0, 0);
      }
    }

    // epilogue: D[row=(lane>>4)*4+r][col=lane&15] (verified layout)
    bool pOut = (flags & 4) != 0;
    unsigned short* YH = (unsigned short*)Yreg;
    unsigned short* YL = YH + (size_t)ROWS * ldy;
#pragma unroll
    for (int nf = 0; nf < 4; nf++) {
      int n = nbase + nf * 16 + lr;
      if (n < Nout) {
        float bv = bias ? us2f(((const unsigned short*)bias)[bOff + n]) : 0.f;
#pragma unroll
        for (int r = 0; r < 4; r++) {
          int m = mbase + w * 16 + lg * 4 + r;
          float v = acc[nf][r] + bv;
          if (flags & 2) v = 0.5f * v * (1.0f + erff(v * 0.70710678118654752f));
          size_t yi = (size_t)m * ldy + n;
          if (pOut) {
            unsigned short h = f2bfu(v);
            YH[yi] = h;
            YL[yi] = f2bfu(v - us2f(h));
          } else {
            float* yp = (float*)Yreg + yi;
            if (flags & 1) v += *yp;
            *yp = v;
          }
        }
      }
    }
  } else {
    // ---------------- scalar fallback (f32 A + f32 weights) ----------------
    float (*As)[64] = (float (*)[64])(void*)sm;
    float (*Ws)[64] = (float (*)[64])(void*)(sm + 4096);
    const float* A = (const float*)Areg;
    float* Y = (float*)Yreg;
    int tx = tid & 15, ty = tid >> 4;
    int am = tid >> 2;
    int ak = (tid & 3) << 2;
    int gn = nbase + am;

    float acc[4][4];
#pragma unroll
    for (int i = 0; i < 4; i++)
#pragma unroll
      for (int j = 0; j < 4; j++) acc[i][j] = 0.f;

    for (int k0 = 0; k0 < K; k0 += 16) {
      float4 av = *(const float4*)(A + (size_t)(mbase + am) * lda + (k0 + ak));
      As[ak + 0][am] = av.x; As[ak + 1][am] = av.y;
      As[ak + 2][am] = av.z; As[ak + 3][am] = av.w;
      float4 wv = make_float4(0.f, 0.f, 0.f, 0.f);
      if (gn < Nout) wv = *(const float4*)((const float*)Wp + wOff + (size_t)gn * K + (k0 + ak));
      Ws[ak + 0][am] = wv.x; Ws[ak + 1][am] = wv.y;
      Ws[ak + 2][am] = wv.z; Ws[ak + 3][am] = wv.w;
      __syncthreads();
#pragma unroll
      for (int kk = 0; kk < 16; kk++) {
        float4 a = *(const float4*)&As[kk][ty << 2];
        float4 w2 = *(const float4*)&Ws[kk][tx << 2];
        acc[0][0] += a.x * w2.x; acc[0][1] += a.x * w2.y; acc[0][2] += a.x * w2.z; acc[0][3] += a.x * w2.w;
        acc[1][0] += a.y * w2.x; acc[1][1] += a.y * w2.y; acc[1][2] += a.y * w2.z; acc[1][3] += a.y * w2.w;
        acc[2][0] += a.z * w2.x; acc[2][1] += a.z * w2.y; acc[2][2] += a.z * w2.z; acc[2][3] += a.z * w2.w;
        acc[3][0] += a.w * w2.x; acc[3][1] += a.w * w2.y; acc[3][2] += a.w * w2.z; acc[3][3] += a.w * w2.w;
      }
      __syncthreads();
    }

    bool pOut = (flags & 4) != 0;
    unsigned short* YH = (unsigned short*)Yreg;
    unsigned short* YL = YH + (size_t)ROWS * ldy;
#pragma unroll
    for (int i = 0; i < 4; i++) {
      int m = mbase + (ty << 2) + i;
#pragma unroll
      for (int j = 0; j < 4; j++) {
        int n = nbase + (tx << 2) + j;
        if (n < Nout) {
          float v = acc[i][j];
          if (bias) v += ((const float*)bias)[bOff + n];
          if (flags & 2) v = 0.5f * v * (1.0f + erff(v * 0.70710678118654752f));
          size_t yi = (size_t)m * ldy + n;
          if (pOut) {
            (void)YH; (void)YL;
            Y[yi] = v;                 // !isbf: consumers read f32
          } else {
            float* yp = Y + yi;
            if (flags & 1) v += *yp;
            *yp = v;
          }
        }
      }
    }
  }
}

// ---------------------------------------------------------------- LayerNorm (dual output)
__global__ __launch_bounds__(256) void ln_kernel(const float* __restrict__ X,
                                                 const void* __restrict__ gs,
                                                 const void* __restrict__ gb,
                                                 size_t gOff,
                                                 float* __restrict__ H,
                                                 const int* __restrict__ dt) {
  bool isbf = (*dt != 0);
  int row = blockIdx.x;
  int tid = threadIdx.x;
  const float* xr = X + (size_t)row * CDIM;
  float v0 = xr[tid], v1 = xr[tid + 256], v2 = xr[tid + 512];
  float sum = waveSum(v0 + v1 + v2);
  __shared__ float red[4];
  __shared__ float statMu;
  __shared__ float statRs;
  int wid = tid >> 6, lane = tid & 63;
  if (lane == 0) red[wid] = sum;
  __syncthreads();
  if (tid == 0) statMu = (red[0] + red[1] + red[2] + red[3]) * (1.0f / 768.0f);
  __syncthreads();
  float mu = statMu;
  float d0 = v0 - mu, d1 = v1 - mu, d2 = v2 - mu;
  float sq = waveSum(d0 * d0 + d1 * d1 + d2 * d2);
  if (lane == 0) red[wid] = sq;
  __syncthreads();
  if (tid == 0)
    statRs = rsqrtf((red[0] + red[1] + red[2] + red[3]) * (1.0f / 768.0f) + 1e-6f);
  __syncthreads();
  float rs = statRs;
  unsigned short* HH = (unsigned short*)H;
  unsigned short* HL = HH + (size_t)ROWS * CDIM;
  size_t rb = (size_t)row * CDIM;
  float o0 = d0 * rs * ldP(gs, gOff + tid, isbf)       + ldP(gb, gOff + tid, isbf);
  float o1 = d1 * rs * ldP(gs, gOff + tid + 256, isbf) + ldP(gb, gOff + tid + 256, isbf);
  float o2 = d2 * rs * ldP(gs, gOff + tid + 512, isbf) + ldP(gb, gOff + tid + 512, isbf);
  stDual(o0, isbf, H, rb + tid, HH, HL);
  stDual(o1, isbf, H, rb + tid + 256, HH, HL);
  stDual(o2, isbf, H, rb + tid + 512, HH, HL);
}

// ---------------------------------------------------------------- deformable attention (dual output)
__global__ __launch_bounds__(256) void deform_kernel(const float* __restrict__ QKV,
                                                     const float* __restrict__ OFFS,
                                                     float* __restrict__ ATT,
                                                     const int* __restrict__ dt) {
  bool isbf = (*dt != 0);
  int gid = blockIdx.x * 4 + (threadIdx.x >> 6);   // < 24576 = 2048*12
  int lane = threadIdx.x & 63;
  int h = gid % NHEAD;
  int bn = gid / NHEAD;          // b*1024 + n
  int n = bn & (NTOK - 1);
  int b = bn >> 10;
  int hp = n >> 5, wp = n & 31;

  float qd = QKV[(size_t)bn * 2304 + h * HEADD + lane];
  const float* orow = OFFS + (size_t)bn * 96 + h * 8;

  float sv[4], sc[4];
#pragma unroll
  for (int p = 0; p < 4; p++) {
    float ox = orow[p * 2 + 0];
    float oy = orow[p * 2 + 1];
    float xx = (float)wp + ox;
    float yy = (float)hp + oy;
    float x0f = floorf(xx), y0f = floorf(yy);
    int x0 = (int)x0f, y0 = (int)y0f;
    float wx = xx - x0f, wy = yy - y0f;
    int xs[2] = {x0, x0 + 1};
    int ys[2] = {y0, y0 + 1};
    float wxs[2] = {1.f - wx, wx};
    float wys[2] = {1.f - wy, wy};
    float skv = 0.f, svv = 0.f;
#pragma unroll
    for (int cy = 0; cy < 2; cy++) {
#pragma unroll
      for (int cx = 0; cx < 2; cx++) {
        int yi = ys[cy], xi = xs[cx];
        if (yi >= 0 && yi < 32 && xi >= 0 && xi < 32) {
          const float* kp = QKV + ((size_t)(b * NTOK + (yi << 5) + xi)) * 2304 + CDIM + h * HEADD + lane;
          float w = wys[cy] * wxs[cx];
          skv += w * kp[0];
          svv += w * kp[CDIM];
        }
      }
    }
    sv[p] = svv;
    sc[p] = waveSum(qd * skv) * SCALE;
  }
  float mx = fmaxf(fmaxf(sc[0], sc[1]), fmaxf(sc[2], sc[3]));
  float e0 = expf(sc[0] - mx), e1 = expf(sc[1] - mx), e2 = expf(sc[2] - mx), e3 = expf(sc[3] - mx);
  float l = e0 + e1 + e2 + e3;
  float od = (e0 * sv[0] + e1 * sv[1] + e2 * sv[2] + e3 * sv[3]) / l;
  unsigned short* AHp = (unsigned short*)ATT;
  unsigned short* ALp = AHp + (size_t)ROWS * CDIM;
  stDual(od, isbf, ATT, (size_t)bn * CDIM + h * HEADD + lane, AHp, ALp);
}

// ---------------------------------------------------------------- full attention (flash partial + combine)
__global__ __launch_bounds__(256) void flash_partial(const float* __restrict__ QKV,
                                                     float* __restrict__ PACC,
                                                     float* __restrict__ PM,
                                                     float* __restrict__ PL) {
  int bid = blockIdx.x;                 // ((b*12+h)*2 + kc)*16 + qb
  int qb = bid & 15;
  int kc = (bid >> 4) & 1;
  int bh = bid >> 5;                    // 0..23 = b*12 + h
  int h = bh % NHEAD;
  int b = bh / NHEAD;
  int tid = threadIdx.x;
  int qi = tid >> 2;
  int dc = (tid & 3) << 4;
  int n = qb * 64 + qi;

  const float* base = QKV + (size_t)b * NTOK * 2304;
  float q[16];
  const float* qp = base + (size_t)n * 2304 + h * HEADD + dc;
#pragma unroll
  for (int j = 0; j < 4; j++) {
    float4 t = *(const float4*)(qp + 4 * j);
    q[4 * j] = t.x; q[4 * j + 1] = t.y; q[4 * j + 2] = t.z; q[4 * j + 3] = t.w;
  }
  float acc[16];
#pragma unroll
  for (int j = 0; j < 16; j++) acc[j] = 0.f;
  float mrun = -INFINITY, l = 0.f;

  __shared__ float Ks[64][68];
  __shared__ float Vs[64][68];

  for (int kt = 0; kt < 8; kt++) {
    int mk = kc * 512 + kt * 64;
    {
      int krow = tid >> 2;
      int d0 = (tid & 3) << 4;
      const float* kp = base + (size_t)(mk + krow) * 2304 + CDIM + h * HEADD + d0;
#pragma unroll
      for (int j = 0; j < 4; j++)
        *(float4*)&Ks[krow][d0 + 4 * j] = *(const float4*)(kp + 4 * j);
      const float* vp = kp + CDIM;
#pragma unroll
      for (int j = 0; j < 4; j++)
        *(float4*)&Vs[krow][d0 + 4 * j] = *(const float4*)(vp + 4 * j);
    }
    __syncthreads();
    for (int m = 0; m < 64; m++) {
      const float* kr = &Ks[m][dc];
      float s0 = 0.f, s1 = 0.f, s2 = 0.f, s3 = 0.f;
#pragma unroll
      for (int j = 0; j < 4; j++) {
        s0 += q[4 * j + 0] * kr[4 * j + 0];
        s1 += q[4 * j + 1] * kr[4 * j + 1];
        s2 += q[4 * j + 2] * kr[4 * j + 2];
        s3 += q[4 * j + 3] * kr[4 * j + 3];
      }
      float s = (s0 + s1) + (s2 + s3);
      s += __shfl_xor(s, 1, 64);
      s += __shfl_xor(s, 2, 64);
      s *= SCALE;
      const float* vr = &Vs[m][dc];
      if (s <= mrun) {
        float p = __expf(s - mrun);
        l += p;
#pragma unroll
        for (int j = 0; j < 16; j++) acc[j] = fmaf(p, vr[j], acc[j]);
      } else {
        float alpha = __expf(mrun - s);
        l = fmaf(l, alpha, 1.f);
#pragma unroll
        for (int j = 0; j < 16; j++) acc[j] = fmaf(acc[j], alpha, vr[j]);
        mrun = s;
      }
    }
    __syncthreads();
  }

  size_t idx = (size_t)(bh * 2 + kc) * NTOK + n;
  if ((tid & 3) == 0) {
    PM[idx] = mrun;
    PL[idx] = l;
  }
  float* ap = PACC + idx * 64 + dc;
#pragma unroll
  for (int j = 0; j < 4; j++) {
    float4 t;
    t.x = acc[4 * j]; t.y = acc[4 * j + 1]; t.z = acc[4 * j + 2]; t.w = acc[4 * j + 3];
    *(float4*)(ap + 4 * j) = t;
  }
}

__global__ __launch_bounds__(256) void flash_combine(const float* __restrict__ PACC,
                                                     const float* __restrict__ PM,
                                                     const float* __restrict__ PL,
                                                     float* __restrict__ ATT,
                                                     const int* __restrict__ dt) {
  bool isbf = (*dt != 0);
  int gid = blockIdx.x * 4 + (threadIdx.x >> 6);
  int lane = threadIdx.x & 63;
  int n = gid & (NTOK - 1);
  int bh = gid >> 10;
  size_t base = (size_t)bh * 2048 + n;
  float m0 = PM[base], m1 = PM[base + 1024];
  float mx = fmaxf(m0, m1);
  float w0 = __expf(m0 - mx), w1 = __expf(m1 - mx);
  float l = w0 * PL[base] + w1 * PL[base + 1024];
  float a = w0 * PACC[base * 64 + lane] + w1 * PACC[(base + 1024) * 64 + lane];
  int b = bh / NHEAD, h = bh - b * NHEAD;
  unsigned short* AHp = (unsigned short*)ATT;
  unsigned short* ALp = AHp + (size_t)ROWS * CDIM;
  stDual(a / l, isbf, ATT, ((size_t)(b * NTOK + n)) * CDIM + h * HEADD + lane, AHp, ALp);
}

// ---------------------------------------------------------------- output transpose (B,N,C)->(B,C,N)
__global__ __launch_bounds__(256) void out_kernel(const float* __restrict__ X,
                                                  void* __restrict__ out,
                                                  const int* __restrict__ dt) {
  bool isbf = (*dt != 0);
  int idx = blockIdx.x * 256 + threadIdx.x;
  int n = idx & (NTOK - 1);
  int rest = idx >> 10;
  int c = rest % CDIM;
  int b = rest / CDIM;
  float v = X[((size_t)(b * NTOK + n)) * CDIM + c];
  if (isbf)
    ((__hip_bfloat16*)out)[idx] = __float2bfloat16(v);
  else
    ((float*)out)[idx] = v;
}

// ---------------------------------------------------------------- launch
extern "C" void kernel_launch(void* const* d_in, const int* in_sizes, int n_in,
                              void* d_out, int out_size, void* d_ws, size_t ws_size,
                              hipStream_t stream) {
  const void* x       = d_in[0];
  const void* patch_w = d_in[1];
  const void* patch_b = d_in[2];
  const void* ln1_s   = d_in[3];
  const void* ln1_b   = d_in[4];
  const void* qkv_w   = d_in[5];
  const void* offs_w  = d_in[6];
  const void* offs_b  = d_in[7];
  const void* proj_w  = d_in[8];
  const void* proj_b  = d_in[9];
  const void* ln2_s   = d_in[10];
  const void* ln2_b   = d_in[11];
  const void* fc1_w   = d_in[12];
  const void* fc1_b   = d_in[13];
  const void* fc2_w   = d_in[14];
  const void* fc2_b   = d_in[15];

  float* W = (float*)d_ws;
  const size_t XSZ = (size_t)ROWS * CDIM;        // 1,572,864 floats
  float* X    = W;                               // residual stream (f32)
  float* Hb   = W + XSZ;                         // LN out (dual region)
  float* ATT  = W + 2 * XSZ;                     // attention out (dual region)
  float* QKV  = W + 3 * XSZ;                     // 2048x2304 f32 (also im2col dual scratch)
  float* BIG  = W + 3 * XSZ + (size_t)ROWS * 2304;  // 2048x3072 (fc1 dual / flash PACC f32)
  float* OFFS = BIG + (size_t)ROWS * 3072;       // 2048x96 f32 (also flash PM/PL region)
  float* PM   = OFFS;
  float* PL   = OFFS + 24 * 4 * NTOK;
  float* Q    = OFFS + 196608;                   // q planes / f32 copy (XSZ)
  int* FLAG   = (int*)(Q + XSZ);

  detect_kernel<<<1, 1, 0, stream>>>(qkv_w, FLAG);

  // patch embed: im2col -> GEMM
  im2col_kernel<<<6144, 256, 0, stream>>>(x, QKV, FLAG);
  gemm_kernel<<<dim3(12, 32), 256, 0, stream>>>(QKV, 768, patch_w, 0, patch_b, 0,
                                                X, 768, 768, 768, 0, FLAG);

  for (int i = 0; i < 6; i++) {
    ln_kernel<<<2048, 256, 0, stream>>>(X, ln1_s, ln1_b, (size_t)i * CDIM, Hb, FLAG);
    gemm_kernel<<<dim3(36, 32), 256, 0, stream>>>(Hb, 768, qkv_w, (size_t)i * 2304 * 768,
                                                  nullptr, 0, QKV, 2304, 2304, 768, 0, FLAG);
    if ((i + 1) % 3 != 0) {
      cvtq_kernel<<<6144, 256, 0, stream>>>(QKV, Q, FLAG);
      gemm_kernel<<<dim3(2, 32), 256, 0, stream>>>(Q, 768, offs_w, (size_t)i * 96 * 768,
                                                   offs_b, (size_t)i * 96, OFFS, 96, 96, 768, 0, FLAG);
      deform_kernel<<<6144, 256, 0, stream>>>(QKV, OFFS, ATT, FLAG);
    } else {
      flash_partial<<<768, 256, 0, stream>>>(QKV, BIG, PM, PL);
      flash_combine<<<6144, 256, 0, stream>>>(BIG, PM, PL, ATT, FLAG);
    }
    gemm_kernel<<<dim3(12, 32), 256, 0, stream>>>(ATT, 768, proj_w, (size_t)i * 768 * 768,
                                                  proj_b, (size_t)i * CDIM, X, 768, 768, 768, 1, FLAG);
    ln_kernel<<<2048, 256, 0, stream>>>(X, ln2_s, ln2_b, (size_t)i * CDIM, Hb, FLAG);
    gemm_kernel<<<dim3(48, 32), 256, 0, stream>>>(Hb, 768, fc1_w, (size_t)i * 3072 * 768,
                                                  fc1_b, (size_t)i * 3072, BIG, 3072, 3072, 768, 6, FLAG);
    gemm_kernel<<<dim3(12, 32), 256, 0, stream>>>(BIG, 3072, fc2_w, (size_t)i * 768 * 3072,
                                                  fc2_b, (size_t)i * CDIM, X, 768, 768, 3072, 1, FLAG);
  }

  out_kernel<<<6144, 256, 0, stream>>>(X, d_out, FLAG);
}

// Round 4
// 2387.560 us; speedup vs baseline: 2.6653x; 1.8798x over previous
//
#include <hip/hip_runtime.h>
#include <hip/hip_bf16.h>
#include <math.h>

// Problem constants
#define NTOK 1024          // Hp*Wp = 32*32
#define CDIM 768
#define BDIM 2
#define ROWS (BDIM*NTOK)   // 2048
#define NHEAD 12
#define HEADD 64
#define SCALE 0.125f       // 64^-0.5

typedef __attribute__((ext_vector_type(8))) __bf16 bfx8;
typedef __attribute__((ext_vector_type(4))) float f32x4;
typedef __attribute__((ext_vector_type(8))) unsigned short u16x8;

__device__ __forceinline__ float us2f(unsigned short u) {
  return __uint_as_float(((unsigned int)u) << 16);
}
__device__ __forceinline__ unsigned short f2bfu(float v) {
  union { __bf16 b; unsigned short u; } c; c.b = (__bf16)v; return c.u;
}
// dtype-flexible scalar load at ELEMENT index i: isbf ? bf16[i] : f32[i]
__device__ __forceinline__ float ldP(const void* p, size_t i, bool isbf) {
  return isbf ? us2f(((const unsigned short*)p)[i]) : ((const float*)p)[i];
}
// split f32 -> bf16 hi + lo planes
__device__ __forceinline__ void stPlanes(float v, size_t idx,
                                         unsigned short* hp, unsigned short* lp) {
  unsigned short h = f2bfu(v);
  hp[idx] = h;
  lp[idx] = f2bfu(v - us2f(h));
}

__device__ __forceinline__ float waveSum(float v) {
#pragma unroll
  for (int off = 32; off; off >>= 1) v += __shfl_xor(v, off, 64);
  return v;
}

// ---------------------------------------------------------------- dtype detector
// bf16 buffer of 0.02-scale gaussians: ~256/256 halfwords have sane exponent.
// f32 buffer: only odd halfwords do (~152/256 expected). Threshold 220 (≈15σ).
__global__ void detect_kernel(const void* __restrict__ probe, int* __restrict__ flag) {
  const unsigned short* u = (const unsigned short*)probe;
  int plaus = 0;
  for (int i = 0; i < 256; i++) {
    int e = (u[i] >> 7) & 0xFF;
    if (e >= 0x60 && e <= 0x8F) plaus++;
  }
  *flag = (plaus >= 220) ? 1 : 0;
}

// ---------------------------------------------------------------- im2col (plane output)
__global__ __launch_bounds__(256) void im2col_kernel(const void* __restrict__ x,
                                                     float* __restrict__ col,
                                                     const int* __restrict__ dt) {
  bool isbf = (*dt != 0);
  int idx = blockIdx.x * 256 + threadIdx.x;     // < 2048*768
  int k = idx % 768;
  int row = idx / 768;
  int n = row & (NTOK - 1);
  int b = row >> 10;
  int ci = k >> 8;
  int rem = k & 255;
  int py = rem >> 4, px = rem & 15;
  int hp = n >> 5, wp = n & 31;
  int iy = hp * 16 + py, ix = wp * 16 + px;
  size_t xi = (((size_t)(b * 3 + ci) * 512) + iy) * 512 + ix;
  float v = ldP(x, xi, isbf);
  unsigned short* colH = (unsigned short*)col;
  unsigned short* colL = colH + (size_t)ROWS * CDIM;
  stPlanes(v, idx, colH, colL);
}

// ---------------------------------------------------------------- q columns -> planes
__global__ __launch_bounds__(256) void cvtq_kernel(const float* __restrict__ QKV,
                                                   float* __restrict__ Q) {
  int idx = blockIdx.x * 256 + threadIdx.x;     // < 2048*768
  int row = idx / 768, c = idx - row * 768;
  float v = QKV[(size_t)row * 2304 + c];
  unsigned short* qh = (unsigned short*)Q;
  unsigned short* ql = qh + (size_t)ROWS * CDIM;
  stPlanes(v, idx, qh, ql);
}

// ---------------------------------------------------------------- GEMM (MFMA, both dtypes)
// Y[m,n](ldy) (+)= A[m,k] @ W[wOff + n, k]^T + bias[bOff + n]
// A always given as bf16 hi/lo planes (AH base; AL = AH + ROWS*lda elems).
// isbf: W native bf16 -> 2 products (ah*w + al*w).
// else: W f32, split to wh/wl during staging -> 3 products (ah*wh + al*wh + ah*wl).
// Tile: M=128 x N=64, BK=32, 4 waves (each 32 rows x 64 cols).
// LDS 24KB: AH@0(8K) AL@8K WH@16K(4K) WL@20K(4K); 16B-unit swizzle u^=(row>>1)&3,
// applied at global source + fragment read; staging writes linear (conflict-free).
// flags: bit0 residual add, bit1 exact GELU, bit2 plane output
__global__ __launch_bounds__(256) void gemm_kernel(
    const unsigned short* __restrict__ Aplanes, int lda,
    const void* __restrict__ Wraw, size_t wOff,
    const void* __restrict__ bias, size_t bOff,
    void* __restrict__ Yreg, int ldy,
    int Nout, int K, int flags, const int* __restrict__ dt) {
  bool isbf = (*dt != 0);
  __shared__ __align__(16) unsigned char sm[24576];
  int tid = threadIdx.x;
  int nbase = blockIdx.x * 64;
  int mbase = blockIdx.y * 128;
  int lane = tid & 63, w = tid >> 6;
  int lr = lane & 15, lg = lane >> 4;

  const unsigned short* AH = Aplanes;
  const unsigned short* AL = AH + (size_t)ROWS * lda;

  int srow = tid >> 2;                               // staging row 0..63
  int swz = (tid & 3) ^ ((srow >> 1) & 3);           // swizzled 16B unit
  size_t gA0 = (size_t)(mbase + srow) * lda + swz * 8;
  size_t gA1 = gA0 + (size_t)64 * lda;
  int gn = nbase + srow; if (gn > Nout - 1) gn = Nout - 1;
  size_t gW = (size_t)gn * K + swz * 8;
  int wr0 = tid * 16;                                // LDS byte offsets (linear)
  int wr1 = wr0 + 4096;

  f32x4 acc[2][4];
#pragma unroll
  for (int i = 0; i < 2; i++)
#pragma unroll
    for (int j = 0; j < 4; j++) acc[i][j] = f32x4{0.f, 0.f, 0.f, 0.f};

  int ub = (lg ^ ((lr >> 1) & 3)) * 16;              // swizzled frag unit (bytes)
  int rmA = (w * 32 + lr) * 64;                      // byte row offset, mf=0

  if (isbf) {
    const unsigned short* Wb = (const unsigned short*)Wraw + wOff;
    u16x8 rA0h = *(const u16x8*)(AH + gA0);
    u16x8 rA1h = *(const u16x8*)(AH + gA1);
    u16x8 rA0l = *(const u16x8*)(AL + gA0);
    u16x8 rA1l = *(const u16x8*)(AL + gA1);
    u16x8 rW   = *(const u16x8*)(Wb + gW);
    for (int k0 = 0; k0 < K; k0 += 32) {
      __syncthreads();
      *(u16x8*)(sm + wr0) = rA0h;
      *(u16x8*)(sm + wr1) = rA1h;
      *(u16x8*)(sm + 8192 + wr0) = rA0l;
      *(u16x8*)(sm + 8192 + wr1) = rA1l;
      *(u16x8*)(sm + 16384 + wr0) = rW;
      int k1 = k0 + 32;
      if (k1 < K) {                                  // prefetch: hides under MFMA
        rA0h = *(const u16x8*)(AH + gA0 + k1);
        rA1h = *(const u16x8*)(AH + gA1 + k1);
        rA0l = *(const u16x8*)(AL + gA0 + k1);
        rA1l = *(const u16x8*)(AL + gA1 + k1);
        rW   = *(const u16x8*)(Wb + gW + k1);
      }
      __syncthreads();
      bfx8 ah0 = *(const bfx8*)(sm + rmA + ub);
      bfx8 ah1 = *(const bfx8*)(sm + rmA + 1024 + ub);
      bfx8 al0 = *(const bfx8*)(sm + 8192 + rmA + ub);
      bfx8 al1 = *(const bfx8*)(sm + 8192 + rmA + 1024 + ub);
#pragma unroll
      for (int nf = 0; nf < 4; nf++) {
        bfx8 wh = *(const bfx8*)(sm + 16384 + (nf * 16 + lr) * 64 + ub);
        acc[0][nf] = __builtin_amdgcn_mfma_f32_16x16x32_bf16(ah0, wh, acc[0][nf], 0, 0, 0);
        acc[0][nf] = __builtin_amdgcn_mfma_f32_16x16x32_bf16(al0, wh, acc[0][nf], 0, 0, 0);
        acc[1][nf] = __builtin_amdgcn_mfma_f32_16x16x32_bf16(ah1, wh, acc[1][nf], 0, 0, 0);
        acc[1][nf] = __builtin_amdgcn_mfma_f32_16x16x32_bf16(al1, wh, acc[1][nf], 0, 0, 0);
      }
    }
  } else {
    const float* Wf = (const float*)Wraw + wOff;
    u16x8 rA0h = *(const u16x8*)(AH + gA0);
    u16x8 rA1h = *(const u16x8*)(AH + gA1);
    u16x8 rA0l = *(const u16x8*)(AL + gA0);
    u16x8 rA1l = *(const u16x8*)(AL + gA1);
    float4 rW0 = *(const float4*)(Wf + gW);
    float4 rW1 = *(const float4*)(Wf + gW + 4);
    for (int k0 = 0; k0 < K; k0 += 32) {
      __syncthreads();
      *(u16x8*)(sm + wr0) = rA0h;
      *(u16x8*)(sm + wr1) = rA1h;
      *(u16x8*)(sm + 8192 + wr0) = rA0l;
      *(u16x8*)(sm + 8192 + wr1) = rA1l;
      {
        float wv[8] = {rW0.x, rW0.y, rW0.z, rW0.w, rW1.x, rW1.y, rW1.z, rW1.w};
        u16x8 wh8, wl8;
#pragma unroll
        for (int i = 0; i < 8; i++) {
          unsigned short h = f2bfu(wv[i]);
          wh8[i] = h;
          wl8[i] = f2bfu(wv[i] - us2f(h));
        }
        *(u16x8*)(sm + 16384 + wr0) = wh8;
        *(u16x8*)(sm + 20480 + wr0) = wl8;
      }
      int k1 = k0 + 32;
      if (k1 < K) {
        rA0h = *(const u16x8*)(AH + gA0 + k1);
        rA1h = *(const u16x8*)(AH + gA1 + k1);
        rA0l = *(const u16x8*)(AL + gA0 + k1);
        rA1l = *(const u16x8*)(AL + gA1 + k1);
        rW0  = *(const float4*)(Wf + gW + k1);
        rW1  = *(const float4*)(Wf + gW + k1 + 4);
      }
      __syncthreads();
      bfx8 ah0 = *(const bfx8*)(sm + rmA + ub);
      bfx8 ah1 = *(const bfx8*)(sm + rmA + 1024 + ub);
      bfx8 al0 = *(const bfx8*)(sm + 8192 + rmA + ub);
      bfx8 al1 = *(const bfx8*)(sm + 8192 + rmA + 1024 + ub);
#pragma unroll
      for (int nf = 0; nf < 4; nf++) {
        int rn = (nf * 16 + lr) * 64 + ub;
        bfx8 wh = *(const bfx8*)(sm + 16384 + rn);
        bfx8 wl = *(const bfx8*)(sm + 20480 + rn);
        acc[0][nf] = __builtin_amdgcn_mfma_f32_16x16x32_bf16(ah0, wh, acc[0][nf], 0, 0, 0);
        acc[0][nf] = __builtin_amdgcn_mfma_f32_16x16x32_bf16(al0, wh, acc[0][nf], 0, 0, 0);
        acc[0][nf] = __builtin_amdgcn_mfma_f32_16x16x32_bf16(ah0, wl, acc[0][nf], 0, 0, 0);
        acc[1][nf] = __builtin_amdgcn_mfma_f32_16x16x32_bf16(ah1, wh, acc[1][nf], 0, 0, 0);
        acc[1][nf] = __builtin_amdgcn_mfma_f32_16x16x32_bf16(al1, wh, acc[1][nf], 0, 0, 0);
        acc[1][nf] = __builtin_amdgcn_mfma_f32_16x16x32_bf16(ah1, wl, acc[1][nf], 0, 0, 0);
      }
    }
  }

  // epilogue: D[row=(lane>>4)*4+r][col=lane&15] per 16x16 frag (verified layout)
  bool pOut = (flags & 4) != 0;
  unsigned short* YH = (unsigned short*)Yreg;
  unsigned short* YL = YH + (size_t)ROWS * ldy;
#pragma unroll
  for (int mf = 0; mf < 2; mf++) {
#pragma unroll
    for (int nf = 0; nf < 4; nf++) {
      int n = nbase + nf * 16 + lr;
      if (n < Nout) {
        float bv = bias ? ldP(bias, bOff + n, isbf) : 0.f;
#pragma unroll
        for (int r = 0; r < 4; r++) {
          int m = mbase + w * 32 + mf * 16 + lg * 4 + r;
          float v = acc[mf][nf][r] + bv;
          if (flags & 2) v = 0.5f * v * (1.0f + erff(v * 0.70710678118654752f));
          size_t yi = (size_t)m * ldy + n;
          if (pOut) {
            unsigned short h = f2bfu(v);
            YH[yi] = h;
            YL[yi] = f2bfu(v - us2f(h));
          } else {
            float* yp = (float*)Yreg + yi;
            if (flags & 1) v += *yp;
            *yp = v;
          }
        }
      }
    }
  }
}

// ---------------------------------------------------------------- LayerNorm (plane output)
__global__ __launch_bounds__(256) void ln_kernel(const float* __restrict__ X,
                                                 const void* __restrict__ gs,
                                                 const void* __restrict__ gb,
                                                 size_t gOff,
                                                 float* __restrict__ H,
                                                 const int* __restrict__ dt) {
  bool isbf = (*dt != 0);
  int row = blockIdx.x;
  int tid = threadIdx.x;
  const float* xr = X + (size_t)row * CDIM;
  float v0 = xr[tid], v1 = xr[tid + 256], v2 = xr[tid + 512];
  float sum = waveSum(v0 + v1 + v2);
  __shared__ float red[4];
  __shared__ float statMu;
  __shared__ float statRs;
  int wid = tid >> 6, lane = tid & 63;
  if (lane == 0) red[wid] = sum;
  __syncthreads();
  if (tid == 0) statMu = (red[0] + red[1] + red[2] + red[3]) * (1.0f / 768.0f);
  __syncthreads();
  float mu = statMu;
  float d0 = v0 - mu, d1 = v1 - mu, d2 = v2 - mu;
  float sq = waveSum(d0 * d0 + d1 * d1 + d2 * d2);
  if (lane == 0) red[wid] = sq;
  __syncthreads();
  if (tid == 0)
    statRs = rsqrtf((red[0] + red[1] + red[2] + red[3]) * (1.0f / 768.0f) + 1e-6f);
  __syncthreads();
  float rs = statRs;
  unsigned short* HH = (unsigned short*)H;
  unsigned short* HL = HH + (size_t)ROWS * CDIM;
  size_t rb = (size_t)row * CDIM;
  float o0 = d0 * rs * ldP(gs, gOff + tid, isbf)       + ldP(gb, gOff + tid, isbf);
  float o1 = d1 * rs * ldP(gs, gOff + tid + 256, isbf) + ldP(gb, gOff + tid + 256, isbf);
  float o2 = d2 * rs * ldP(gs, gOff + tid + 512, isbf) + ldP(gb, gOff + tid + 512, isbf);
  stPlanes(o0, rb + tid, HH, HL);
  stPlanes(o1, rb + tid + 256, HH, HL);
  stPlanes(o2, rb + tid + 512, HH, HL);
}

// ---------------------------------------------------------------- deformable attention (plane output)
__global__ __launch_bounds__(256) void deform_kernel(const float* __restrict__ QKV,
                                                     const float* __restrict__ OFFS,
                                                     float* __restrict__ ATT) {
  int gid = blockIdx.x * 4 + (threadIdx.x >> 6);   // < 24576 = 2048*12
  int lane = threadIdx.x & 63;
  int h = gid % NHEAD;
  int bn = gid / NHEAD;          // b*1024 + n
  int n = bn & (NTOK - 1);
  int b = bn >> 10;
  int hp = n >> 5, wp = n & 31;

  float qd = QKV[(size_t)bn * 2304 + h * HEADD + lane];
  const float* orow = OFFS + (size_t)bn * 96 + h * 8;

  float sv[4], sc[4];
#pragma unroll
  for (int p = 0; p < 4; p++) {
    float ox = orow[p * 2 + 0];
    float oy = orow[p * 2 + 1];
    float xx = (float)wp + ox;
    float yy = (float)hp + oy;
    float x0f = floorf(xx), y0f = floorf(yy);
    int x0 = (int)x0f, y0 = (int)y0f;
    float wx = xx - x0f, wy = yy - y0f;
    int xs[2] = {x0, x0 + 1};
    int ys[2] = {y0, y0 + 1};
    float wxs[2] = {1.f - wx, wx};
    float wys[2] = {1.f - wy, wy};
    float skv = 0.f, svv = 0.f;
#pragma unroll
    for (int cy = 0; cy < 2; cy++) {
#pragma unroll
      for (int cx = 0; cx < 2; cx++) {
        int yi = ys[cy], xi = xs[cx];
        if (yi >= 0 && yi < 32 && xi >= 0 && xi < 32) {
          const float* kp = QKV + ((size_t)(b * NTOK + (yi << 5) + xi)) * 2304 + CDIM + h * HEADD + lane;
          float w = wys[cy] * wxs[cx];
          skv += w * kp[0];
          svv += w * kp[CDIM];
        }
      }
    }
    sv[p] = svv;
    sc[p] = waveSum(qd * skv) * SCALE;
  }
  float mx = fmaxf(fmaxf(sc[0], sc[1]), fmaxf(sc[2], sc[3]));
  float e0 = expf(sc[0] - mx), e1 = expf(sc[1] - mx), e2 = expf(sc[2] - mx), e3 = expf(sc[3] - mx);
  float l = e0 + e1 + e2 + e3;
  float od = (e0 * sv[0] + e1 * sv[1] + e2 * sv[2] + e3 * sv[3]) / l;
  unsigned short* AHp = (unsigned short*)ATT;
  unsigned short* ALp = AHp + (size_t)ROWS * CDIM;
  stPlanes(od, (size_t)bn * CDIM + h * HEADD + lane, AHp, ALp);
}

// ---------------------------------------------------------------- full attention (flash partial + combine)
__global__ __launch_bounds__(256) void flash_partial(const float* __restrict__ QKV,
                                                     float* __restrict__ PACC,
                                                     float* __restrict__ PM,
                                                     float* __restrict__ PL) {
  int bid = blockIdx.x;                 // ((b*12+h)*2 + kc)*16 + qb
  int qb = bid & 15;
  int kc = (bid >> 4) & 1;
  int bh = bid >> 5;                    // 0..23 = b*12 + h
  int h = bh % NHEAD;
  int b = bh / NHEAD;
  int tid = threadIdx.x;
  int qi = tid >> 2;
  int dc = (tid & 3) << 4;
  int n = qb * 64 + qi;

  const float* base = QKV + (size_t)b * NTOK * 2304;
  float q[16];
  const float* qp = base + (size_t)n * 2304 + h * HEADD + dc;
#pragma unroll
  for (int j = 0; j < 4; j++) {
    float4 t = *(const float4*)(qp + 4 * j);
    q[4 * j] = t.x; q[4 * j + 1] = t.y; q[4 * j + 2] = t.z; q[4 * j + 3] = t.w;
  }
  float acc[16];
#pragma unroll
  for (int j = 0; j < 16; j++) acc[j] = 0.f;
  float mrun = -INFINITY, l = 0.f;

  __shared__ float Ks[64][68];
  __shared__ float Vs[64][68];

  for (int kt = 0; kt < 8; kt++) {
    int mk = kc * 512 + kt * 64;
    {
      int krow = tid >> 2;
      int d0 = (tid & 3) << 4;
      const float* kp = base + (size_t)(mk + krow) * 2304 + CDIM + h * HEADD + d0;
#pragma unroll
      for (int j = 0; j < 4; j++)
        *(float4*)&Ks[krow][d0 + 4 * j] = *(const float4*)(kp + 4 * j);
      const float* vp = kp + CDIM;
#pragma unroll
      for (int j = 0; j < 4; j++)
        *(float4*)&Vs[krow][d0 + 4 * j] = *(const float4*)(vp + 4 * j);
    }
    __syncthreads();
    for (int m = 0; m < 64; m++) {
      const float* kr = &Ks[m][dc];
      float s0 = 0.f, s1 = 0.f, s2 = 0.f, s3 = 0.f;
#pragma unroll
      for (int j = 0; j < 4; j++) {
        s0 += q[4 * j + 0] * kr[4 * j + 0];
        s1 += q[4 * j + 1] * kr[4 * j + 1];
        s2 += q[4 * j + 2] * kr[4 * j + 2];
        s3 += q[4 * j + 3] * kr[4 * j + 3];
      }
      float s = (s0 + s1) + (s2 + s3);
      s += __shfl_xor(s, 1, 64);
      s += __shfl_xor(s, 2, 64);
      s *= SCALE;
      const float* vr = &Vs[m][dc];
      if (s <= mrun) {
        float p = __expf(s - mrun);
        l += p;
#pragma unroll
        for (int j = 0; j < 16; j++) acc[j] = fmaf(p, vr[j], acc[j]);
      } else {
        float alpha = __expf(mrun - s);
        l = fmaf(l, alpha, 1.f);
#pragma unroll
        for (int j = 0; j < 16; j++) acc[j] = fmaf(acc[j], alpha, vr[j]);
        mrun = s;
      }
    }
    __syncthreads();
  }

  size_t idx = (size_t)(bh * 2 + kc) * NTOK + n;
  if ((tid & 3) == 0) {
    PM[idx] = mrun;
    PL[idx] = l;
  }
  float* ap = PACC + idx * 64 + dc;
#pragma unroll
  for (int j = 0; j < 4; j++) {
    float4 t;
    t.x = acc[4 * j]; t.y = acc[4 * j + 1]; t.z = acc[4 * j + 2]; t.w = acc[4 * j + 3];
    *(float4*)(ap + 4 * j) = t;
  }
}

__global__ __launch_bounds__(256) void flash_combine(const float* __restrict__ PACC,
                                                     const float* __restrict__ PM,
                                                     const float* __restrict__ PL,
                                                     float* __restrict__ ATT) {
  int gid = blockIdx.x * 4 + (threadIdx.x >> 6);
  int lane = threadIdx.x & 63;
  int n = gid & (NTOK - 1);
  int bh = gid >> 10;
  size_t base = (size_t)bh * 2048 + n;
  float m0 = PM[base], m1 = PM[base + 1024];
  float mx = fmaxf(m0, m1);
  float w0 = __expf(m0 - mx), w1 = __expf(m1 - mx);
  float l = w0 * PL[base] + w1 * PL[base + 1024];
  float a = w0 * PACC[base * 64 + lane] + w1 * PACC[(base + 1024) * 64 + lane];
  int b = bh / NHEAD, h = bh - b * NHEAD;
  unsigned short* AHp = (unsigned short*)ATT;
  unsigned short* ALp = AHp + (size_t)ROWS * CDIM;
  stPlanes(a / l, ((size_t)(b * NTOK + n)) * CDIM + h * HEADD + lane, AHp, ALp);
}

// ---------------------------------------------------------------- output transpose (B,N,C)->(B,C,N)
__global__ __launch_bounds__(256) void out_kernel(const float* __restrict__ X,
                                                  void* __restrict__ out,
                                                  const int* __restrict__ dt) {
  bool isbf = (*dt != 0);
  int idx = blockIdx.x * 256 + threadIdx.x;
  int n = idx & (NTOK - 1);
  int rest = idx >> 10;
  int c = rest % CDIM;
  int b = rest / CDIM;
  float v = X[((size_t)(b * NTOK + n)) * CDIM + c];
  if (isbf)
    ((__hip_bfloat16*)out)[idx] = __float2bfloat16(v);
  else
    ((float*)out)[idx] = v;
}

// ---------------------------------------------------------------- launch
extern "C" void kernel_launch(void* const* d_in, const int* in_sizes, int n_in,
                              void* d_out, int out_size, void* d_ws, size_t ws_size,
                              hipStream_t stream) {
  const void* x       = d_in[0];
  const void* patch_w = d_in[1];
  const void* patch_b = d_in[2];
  const void* ln1_s   = d_in[3];
  const void* ln1_b   = d_in[4];
  const void* qkv_w   = d_in[5];
  const void* offs_w  = d_in[6];
  const void* offs_b  = d_in[7];
  const void* proj_w  = d_in[8];
  const void* proj_b  = d_in[9];
  const void* ln2_s   = d_in[10];
  const void* ln2_b   = d_in[11];
  const void* fc1_w   = d_in[12];
  const void* fc1_b   = d_in[13];
  const void* fc2_w   = d_in[14];
  const void* fc2_b   = d_in[15];

  float* W = (float*)d_ws;
  const size_t XSZ = (size_t)ROWS * CDIM;        // 1,572,864 floats
  float* X    = W;                               // residual stream (f32)
  float* Hb   = W + XSZ;                         // LN out (bf16 hi/lo planes)
  float* ATT  = W + 2 * XSZ;                     // attention out (planes)
  float* QKV  = W + 3 * XSZ;                     // 2048x2304 f32 (also im2col plane scratch)
  float* BIG  = W + 3 * XSZ + (size_t)ROWS * 2304;  // 2048x3072 (fc1 planes / flash PACC f32)
  float* OFFS = BIG + (size_t)ROWS * 3072;       // 2048x96 f32 (also flash PM/PL region)
  float* PM   = OFFS;
  float* PL   = OFFS + 24 * 4 * NTOK;
  float* Q    = OFFS + 196608;                   // q planes (XSZ floats region)
  int* FLAG   = (int*)(Q + XSZ);

  detect_kernel<<<1, 1, 0, stream>>>(qkv_w, FLAG);

  // patch embed: im2col (planes) -> GEMM
  im2col_kernel<<<6144, 256, 0, stream>>>(x, QKV, FLAG);
  gemm_kernel<<<dim3(12, 16), 256, 0, stream>>>((const unsigned short*)QKV, 768, patch_w, 0,
                                                patch_b, 0, X, 768, 768, 768, 0, FLAG);

  for (int i = 0; i < 6; i++) {
    ln_kernel<<<2048, 256, 0, stream>>>(X, ln1_s, ln1_b, (size_t)i * CDIM, Hb, FLAG);
    gemm_kernel<<<dim3(36, 16), 256, 0, stream>>>((const unsigned short*)Hb, 768, qkv_w,
                                                  (size_t)i * 2304 * 768,
                                                  nullptr, 0, QKV, 2304, 2304, 768, 0, FLAG);
    if ((i + 1) % 3 != 0) {
      cvtq_kernel<<<6144, 256, 0, stream>>>(QKV, Q);
      gemm_kernel<<<dim3(2, 16), 256, 0, stream>>>((const unsigned short*)Q, 768, offs_w,
                                                   (size_t)i * 96 * 768,
                                                   offs_b, (size_t)i * 96, OFFS, 96, 96, 768, 0, FLAG);
      deform_kernel<<<6144, 256, 0, stream>>>(QKV, OFFS, ATT);
    } else {
      flash_partial<<<768, 256, 0, stream>>>(QKV, BIG, PM, PL);
      flash_combine<<<6144, 256, 0, stream>>>(BIG, PM, PL, ATT);
    }
    gemm_kernel<<<dim3(12, 16), 256, 0, stream>>>((const unsigned short*)ATT, 768, proj_w,
                                                  (size_t)i * 768 * 768,
                                                  proj_b, (size_t)i * CDIM, X, 768, 768, 768, 1, FLAG);
    ln_kernel<<<2048, 256, 0, stream>>>(X, ln2_s, ln2_b, (size_t)i * CDIM, Hb, FLAG);
    gemm_kernel<<<dim3(48, 16), 256, 0, stream>>>((const unsigned short*)Hb, 768, fc1_w,
                                                  (size_t)i * 3072 * 768,
                                                  fc1_b, (size_t)i * 3072, BIG, 3072, 3072, 768, 6, FLAG);
    gemm_kernel<<<dim3(12, 16), 256, 0, stream>>>((const unsigned short*)BIG, 3072, fc2_w,
                                                  (size_t)i * 768 * 3072,
                                                  fc2_b, (size_t)i * CDIM, X, 768, 768, 3072, 1, FLAG);
  }

  out_kernel<<<6144, 256, 0, stream>>>(X, d_out, FLAG);
}

// Round 6
// 2065.250 us; speedup vs baseline: 3.0813x; 1.1561x over previous
//
#include <hip/hip_runtime.h>
#include <hip/hip_bf16.h>
#include <math.h>

// Problem constants
#define NTOK 1024          // Hp*Wp = 32*32
#define CDIM 768
#define BDIM 2
#define ROWS (BDIM*NTOK)   // 2048
#define NHEAD 12
#define HEADD 64
#define SCALE 0.125f       // 64^-0.5

typedef __attribute__((ext_vector_type(8))) __bf16 bfx8;
typedef __attribute__((ext_vector_type(4))) float f32x4;
typedef __attribute__((ext_vector_type(8))) unsigned short u16x8;
typedef __attribute__((ext_vector_type(4))) unsigned short u16x4;

__device__ __forceinline__ float us2f(unsigned short u) {
  return __uint_as_float(((unsigned int)u) << 16);
}
__device__ __forceinline__ unsigned short f2bfu(float v) {
  union { __bf16 b; unsigned short u; } c; c.b = (__bf16)v; return c.u;
}
// dtype-flexible scalar load at ELEMENT index i: isbf ? bf16[i] : f32[i]
__device__ __forceinline__ float ldP(const void* p, size_t i, bool isbf) {
  return isbf ? us2f(((const unsigned short*)p)[i]) : ((const float*)p)[i];
}
// split f32 -> bf16 hi + lo planes
__device__ __forceinline__ void stPlanes(float v, size_t idx,
                                         unsigned short* hp, unsigned short* lp) {
  unsigned short h = f2bfu(v);
  hp[idx] = h;
  lp[idx] = f2bfu(v - us2f(h));
}

__device__ __forceinline__ float waveSum(float v) {
#pragma unroll
  for (int off = 32; off; off >>= 1) v += __shfl_xor(v, off, 64);
  return v;
}

// ---------------------------------------------------------------- dtype detector
// bf16 buffer of 0.02-scale gaussians: ~256/256 halfwords have sane exponent.
// f32 buffer: only odd halfwords do (~152/256 expected). Threshold 220 (≈15σ).
__global__ void detect_kernel(const void* __restrict__ probe, int* __restrict__ flag) {
  const unsigned short* u = (const unsigned short*)probe;
  int plaus = 0;
  for (int i = 0; i < 256; i++) {
    int e = (u[i] >> 7) & 0xFF;
    if (e >= 0x60 && e <= 0x8F) plaus++;
  }
  *flag = (plaus >= 220) ? 1 : 0;
}

// ---------------------------------------------------------------- im2col (plane output)
__global__ __launch_bounds__(256) void im2col_kernel(const void* __restrict__ x,
                                                     float* __restrict__ col,
                                                     const int* __restrict__ dt) {
  bool isbf = (*dt != 0);
  int idx = blockIdx.x * 256 + threadIdx.x;     // < 2048*768
  int k = idx % 768;
  int row = idx / 768;
  int n = row & (NTOK - 1);
  int b = row >> 10;
  int ci = k >> 8;
  int rem = k & 255;
  int py = rem >> 4, px = rem & 15;
  int hp = n >> 5, wp = n & 31;
  int iy = hp * 16 + py, ix = wp * 16 + px;
  size_t xi = (((size_t)(b * 3 + ci) * 512) + iy) * 512 + ix;
  float v = ldP(x, xi, isbf);
  unsigned short* colH = (unsigned short*)col;
  unsigned short* colL = colH + (size_t)ROWS * CDIM;
  stPlanes(v, idx, colH, colL);
}

// ---------------------------------------------------------------- q columns -> planes
__global__ __launch_bounds__(256) void cvtq_kernel(const float* __restrict__ QKV,
                                                   float* __restrict__ Q) {
  int idx = blockIdx.x * 256 + threadIdx.x;     // < 2048*768
  int row = idx / 768, c = idx - row * 768;
  float v = QKV[(size_t)row * 2304 + c];
  unsigned short* qh = (unsigned short*)Q;
  unsigned short* ql = qh + (size_t)ROWS * CDIM;
  stPlanes(v, idx, qh, ql);
}

// ---------------------------------------------------------------- GEMM (MFMA, both dtypes)
// Y[m,n](ldy) (+)= A[m,k] @ W[wOff + n, k]^T + bias[bOff + n]
// A always given as bf16 hi/lo planes (AH base; AL = AH + ROWS*lda elems).
// isbf: W native bf16 -> 2 products (ah*w + al*w).
// else: W f32, split to wh/wl during staging -> 3 products (ah*wh + al*wh + ah*wl).
// Tile: M=128 x N=64, BK=32, 4 waves (each 32 rows x 64 cols).
// LDS 24KB: AH@0(8K) AL@8K WH@16K(4K) WL@20K(4K); 16B-unit swizzle u^=(row>>1)&3,
// applied at global source + fragment read; staging writes linear (conflict-free).
// flags: bit0 residual add, bit1 exact GELU, bit2 plane output
__global__ __launch_bounds__(256) void gemm_kernel(
    const unsigned short* __restrict__ Aplanes, int lda,
    const void* __restrict__ Wraw, size_t wOff,
    const void* __restrict__ bias, size_t bOff,
    void* __restrict__ Yreg, int ldy,
    int Nout, int K, int flags, const int* __restrict__ dt) {
  bool isbf = (*dt != 0);
  __shared__ __align__(16) unsigned char sm[24576];
  int tid = threadIdx.x;
  int nbase = blockIdx.x * 64;
  int mbase = blockIdx.y * 128;
  int lane = tid & 63, w = tid >> 6;
  int lr = lane & 15, lg = lane >> 4;

  const unsigned short* AH = Aplanes;
  const unsigned short* AL = AH + (size_t)ROWS * lda;

  int srow = tid >> 2;                               // staging row 0..63
  int swz = (tid & 3) ^ ((srow >> 1) & 3);           // swizzled 16B unit
  size_t gA0 = (size_t)(mbase + srow) * lda + swz * 8;
  size_t gA1 = gA0 + (size_t)64 * lda;
  int gn = nbase + srow; if (gn > Nout - 1) gn = Nout - 1;
  size_t gW = (size_t)gn * K + swz * 8;
  int wr0 = tid * 16;                                // LDS byte offsets (linear)
  int wr1 = wr0 + 4096;

  f32x4 acc[2][4];
#pragma unroll
  for (int i = 0; i < 2; i++)
#pragma unroll
    for (int j = 0; j < 4; j++) acc[i][j] = f32x4{0.f, 0.f, 0.f, 0.f};

  int ub = (lg ^ ((lr >> 1) & 3)) * 16;              // swizzled frag unit (bytes)
  int rmA = (w * 32 + lr) * 64;                      // byte row offset, mf=0

  if (isbf) {
    const unsigned short* Wb = (const unsigned short*)Wraw + wOff;
    u16x8 rA0h = *(const u16x8*)(AH + gA0);
    u16x8 rA1h = *(const u16x8*)(AH + gA1);
    u16x8 rA0l = *(const u16x8*)(AL + gA0);
    u16x8 rA1l = *(const u16x8*)(AL + gA1);
    u16x8 rW   = *(const u16x8*)(Wb + gW);
    for (int k0 = 0; k0 < K; k0 += 32) {
      __syncthreads();
      *(u16x8*)(sm + wr0) = rA0h;
      *(u16x8*)(sm + wr1) = rA1h;
      *(u16x8*)(sm + 8192 + wr0) = rA0l;
      *(u16x8*)(sm + 8192 + wr1) = rA1l;
      *(u16x8*)(sm + 16384 + wr0) = rW;
      int k1 = k0 + 32;
      if (k1 < K) {                                  // prefetch: hides under MFMA
        rA0h = *(const u16x8*)(AH + gA0 + k1);
        rA1h = *(const u16x8*)(AH + gA1 + k1);
        rA0l = *(const u16x8*)(AL + gA0 + k1);
        rA1l = *(const u16x8*)(AL + gA1 + k1);
        rW   = *(const u16x8*)(Wb + gW + k1);
      }
      __syncthreads();
      bfx8 ah0 = *(const bfx8*)(sm + rmA + ub);
      bfx8 ah1 = *(const bfx8*)(sm + rmA + 1024 + ub);
      bfx8 al0 = *(const bfx8*)(sm + 8192 + rmA + ub);
      bfx8 al1 = *(const bfx8*)(sm + 8192 + rmA + 1024 + ub);
#pragma unroll
      for (int nf = 0; nf < 4; nf++) {
        bfx8 wh = *(const bfx8*)(sm + 16384 + (nf * 16 + lr) * 64 + ub);
        acc[0][nf] = __builtin_amdgcn_mfma_f32_16x16x32_bf16(ah0, wh, acc[0][nf], 0, 0, 0);
        acc[0][nf] = __builtin_amdgcn_mfma_f32_16x16x32_bf16(al0, wh, acc[0][nf], 0, 0, 0);
        acc[1][nf] = __builtin_amdgcn_mfma_f32_16x16x32_bf16(ah1, wh, acc[1][nf], 0, 0, 0);
        acc[1][nf] = __builtin_amdgcn_mfma_f32_16x16x32_bf16(al1, wh, acc[1][nf], 0, 0, 0);
      }
    }
  } else {
    const float* Wf = (const float*)Wraw + wOff;
    u16x8 rA0h = *(const u16x8*)(AH + gA0);
    u16x8 rA1h = *(const u16x8*)(AH + gA1);
    u16x8 rA0l = *(const u16x8*)(AL + gA0);
    u16x8 rA1l = *(const u16x8*)(AL + gA1);
    float4 rW0 = *(const float4*)(Wf + gW);
    float4 rW1 = *(const float4*)(Wf + gW + 4);
    for (int k0 = 0; k0 < K; k0 += 32) {
      __syncthreads();
      *(u16x8*)(sm + wr0) = rA0h;
      *(u16x8*)(sm + wr1) = rA1h;
      *(u16x8*)(sm + 8192 + wr0) = rA0l;
      *(u16x8*)(sm + 8192 + wr1) = rA1l;
      {
        float wv[8] = {rW0.x, rW0.y, rW0.z, rW0.w, rW1.x, rW1.y, rW1.z, rW1.w};
        u16x8 wh8, wl8;
#pragma unroll
        for (int i = 0; i < 8; i++) {
          unsigned short h = f2bfu(wv[i]);
          wh8[i] = h;
          wl8[i] = f2bfu(wv[i] - us2f(h));
        }
        *(u16x8*)(sm + 16384 + wr0) = wh8;
        *(u16x8*)(sm + 20480 + wr0) = wl8;
      }
      int k1 = k0 + 32;
      if (k1 < K) {
        rA0h = *(const u16x8*)(AH + gA0 + k1);
        rA1h = *(const u16x8*)(AH + gA1 + k1);
        rA0l = *(const u16x8*)(AL + gA0 + k1);
        rA1l = *(const u16x8*)(AL + gA1 + k1);
        rW0  = *(const float4*)(Wf + gW + k1);
        rW1  = *(const float4*)(Wf + gW + k1 + 4);
      }
      __syncthreads();
      bfx8 ah0 = *(const bfx8*)(sm + rmA + ub);
      bfx8 ah1 = *(const bfx8*)(sm + rmA + 1024 + ub);
      bfx8 al0 = *(const bfx8*)(sm + 8192 + rmA + ub);
      bfx8 al1 = *(const bfx8*)(sm + 8192 + rmA + 1024 + ub);
#pragma unroll
      for (int nf = 0; nf < 4; nf++) {
        int rn = (nf * 16 + lr) * 64 + ub;
        bfx8 wh = *(const bfx8*)(sm + 16384 + rn);
        bfx8 wl = *(const bfx8*)(sm + 20480 + rn);
        acc[0][nf] = __builtin_amdgcn_mfma_f32_16x16x32_bf16(ah0, wh, acc[0][nf], 0, 0, 0);
        acc[0][nf] = __builtin_amdgcn_mfma_f32_16x16x32_bf16(al0, wh, acc[0][nf], 0, 0, 0);
        acc[0][nf] = __builtin_amdgcn_mfma_f32_16x16x32_bf16(ah0, wl, acc[0][nf], 0, 0, 0);
        acc[1][nf] = __builtin_amdgcn_mfma_f32_16x16x32_bf16(ah1, wh, acc[1][nf], 0, 0, 0);
        acc[1][nf] = __builtin_amdgcn_mfma_f32_16x16x32_bf16(al1, wh, acc[1][nf], 0, 0, 0);
        acc[1][nf] = __builtin_amdgcn_mfma_f32_16x16x32_bf16(ah1, wl, acc[1][nf], 0, 0, 0);
      }
    }
  }

  // epilogue: D[row=(lane>>4)*4+r][col=lane&15] per 16x16 frag (verified layout)
  bool pOut = (flags & 4) != 0;
  unsigned short* YH = (unsigned short*)Yreg;
  unsigned short* YL = YH + (size_t)ROWS * ldy;
#pragma unroll
  for (int mf = 0; mf < 2; mf++) {
#pragma unroll
    for (int nf = 0; nf < 4; nf++) {
      int n = nbase + nf * 16 + lr;
      if (n < Nout) {
        float bv = bias ? ldP(bias, bOff + n, isbf) : 0.f;
#pragma unroll
        for (int r = 0; r < 4; r++) {
          int m = mbase + w * 32 + mf * 16 + lg * 4 + r;
          float v = acc[mf][nf][r] + bv;
          if (flags & 2) v = 0.5f * v * (1.0f + erff(v * 0.70710678118654752f));
          size_t yi = (size_t)m * ldy + n;
          if (pOut) {
            unsigned short h = f2bfu(v);
            YH[yi] = h;
            YL[yi] = f2bfu(v - us2f(h));
          } else {
            float* yp = (float*)Yreg + yi;
            if (flags & 1) v += *yp;
            *yp = v;
          }
        }
      }
    }
  }
}

// ---------------------------------------------------------------- LayerNorm (plane output)
__global__ __launch_bounds__(256) void ln_kernel(const float* __restrict__ X,
                                                 const void* __restrict__ gs,
                                                 const void* __restrict__ gb,
                                                 size_t gOff,
                                                 float* __restrict__ H,
                                                 const int* __restrict__ dt) {
  bool isbf = (*dt != 0);
  int row = blockIdx.x;
  int tid = threadIdx.x;
  const float* xr = X + (size_t)row * CDIM;
  float v0 = xr[tid], v1 = xr[tid + 256], v2 = xr[tid + 512];
  float sum = waveSum(v0 + v1 + v2);
  __shared__ float red[4];
  __shared__ float statMu;
  __shared__ float statRs;
  int wid = tid >> 6, lane = tid & 63;
  if (lane == 0) red[wid] = sum;
  __syncthreads();
  if (tid == 0) statMu = (red[0] + red[1] + red[2] + red[3]) * (1.0f / 768.0f);
  __syncthreads();
  float mu = statMu;
  float d0 = v0 - mu, d1 = v1 - mu, d2 = v2 - mu;
  float sq = waveSum(d0 * d0 + d1 * d1 + d2 * d2);
  if (lane == 0) red[wid] = sq;
  __syncthreads();
  if (tid == 0)
    statRs = rsqrtf((red[0] + red[1] + red[2] + red[3]) * (1.0f / 768.0f) + 1e-6f);
  __syncthreads();
  float rs = statRs;
  unsigned short* HH = (unsigned short*)H;
  unsigned short* HL = HH + (size_t)ROWS * CDIM;
  size_t rb = (size_t)row * CDIM;
  float o0 = d0 * rs * ldP(gs, gOff + tid, isbf)       + ldP(gb, gOff + tid, isbf);
  float o1 = d1 * rs * ldP(gs, gOff + tid + 256, isbf) + ldP(gb, gOff + tid + 256, isbf);
  float o2 = d2 * rs * ldP(gs, gOff + tid + 512, isbf) + ldP(gb, gOff + tid + 512, isbf);
  stPlanes(o0, rb + tid, HH, HL);
  stPlanes(o1, rb + tid + 256, HH, HL);
  stPlanes(o2, rb + tid + 512, HH, HL);
}

// ---------------------------------------------------------------- deformable attention (plane output)
__global__ __launch_bounds__(256) void deform_kernel(const float* __restrict__ QKV,
                                                     const float* __restrict__ OFFS,
                                                     float* __restrict__ ATT) {
  int gid = blockIdx.x * 4 + (threadIdx.x >> 6);   // < 24576 = 2048*12
  int lane = threadIdx.x & 63;
  int h = gid % NHEAD;
  int bn = gid / NHEAD;          // b*1024 + n
  int n = bn & (NTOK - 1);
  int b = bn >> 10;
  int hp = n >> 5, wp = n & 31;

  float qd = QKV[(size_t)bn * 2304 + h * HEADD + lane];
  const float* orow = OFFS + (size_t)bn * 96 + h * 8;

  float sv[4], sc[4];
#pragma unroll
  for (int p = 0; p < 4; p++) {
    float ox = orow[p * 2 + 0];
    float oy = orow[p * 2 + 1];
    float xx = (float)wp + ox;
    float yy = (float)hp + oy;
    float x0f = floorf(xx), y0f = floorf(yy);
    int x0 = (int)x0f, y0 = (int)y0f;
    float wx = xx - x0f, wy = yy - y0f;
    int xs[2] = {x0, x0 + 1};
    int ys[2] = {y0, y0 + 1};
    float wxs[2] = {1.f - wx, wx};
    float wys[2] = {1.f - wy, wy};
    float skv = 0.f, svv = 0.f;
#pragma unroll
    for (int cy = 0; cy < 2; cy++) {
#pragma unroll
      for (int cx = 0; cx < 2; cx++) {
        int yi = ys[cy], xi = xs[cx];
        if (yi >= 0 && yi < 32 && xi >= 0 && xi < 32) {
          const float* kp = QKV + ((size_t)(b * NTOK + (yi << 5) + xi)) * 2304 + CDIM + h * HEADD + lane;
          float w = wys[cy] * wxs[cx];
          skv += w * kp[0];
          svv += w * kp[CDIM];
        }
      }
    }
    sv[p] = svv;
    sc[p] = waveSum(qd * skv) * SCALE;
  }
  float mx = fmaxf(fmaxf(sc[0], sc[1]), fmaxf(sc[2], sc[3]));
  float e0 = expf(sc[0] - mx), e1 = expf(sc[1] - mx), e2 = expf(sc[2] - mx), e3 = expf(sc[3] - mx);
  float l = e0 + e1 + e2 + e3;
  float od = (e0 * sv[0] + e1 * sv[1] + e2 * sv[2] + e3 * sv[3]) / l;
  unsigned short* AHp = (unsigned short*)ATT;
  unsigned short* ALp = AHp + (size_t)ROWS * CDIM;
  stPlanes(od, (size_t)bn * CDIM + h * HEADD + lane, AHp, ALp);
}

// ---------------------------------------------------------------- full attention (MFMA flash partial + combine)
// Per block: 64 queries (qb) x 512 keys (kc), 4 waves; wave owns 16 q, all keys.
// S^T = K·Q^T (A=K rows, B=Q regs; D: col=lane&15=q, row=4*lg+r=key) ->
// in-register online softmax (2 shfl_xor). P round-trips through per-wave LDS
// (consecutive-key u16x4 writes, natural-order A-frag reads). V staged
// TRANSPOSED (VT[d][key] hi/lo) so B-frags are single ds_read_b128.
// All LDS banked via 16B-unit XOR swizzle (phys = unit ^ (row&7)).
// hi/lo bf16 split on both products (3 MFMAs each) for ~2^-17 rel precision.
__global__ __launch_bounds__(256) void flash_partial(const float* __restrict__ QKV,
                                                     float* __restrict__ PACC,
                                                     float* __restrict__ PM,
                                                     float* __restrict__ PL) {
  int bid = blockIdx.x;                 // ((b*12+h)*2 + kc)*16 + qb
  int qb = bid & 15;
  int kc = (bid >> 4) & 1;
  int bh = bid >> 5;                    // 0..23 = b*12 + h
  int h = bh % NHEAD;
  int b = bh / NHEAD;
  int tid = threadIdx.x;
  int lane = tid & 63, wq = tid >> 6;
  int lr = lane & 15, lg = lane >> 4;

  __shared__ __align__(16) unsigned short KH[64 * 72];   // K rows padded: 144B = 9x16B
  __shared__ __align__(16) unsigned short KL[64 * 72];
  __shared__ __align__(16) unsigned short VTH[64 * 64];  // V^T [d][key], swizzled units
  __shared__ __align__(16) unsigned short VTL[64 * 64];
  __shared__ __align__(16) unsigned short PH[4 * 16 * 64]; // per-wave P [q][key]
  __shared__ __align__(16) unsigned short PL_[4 * 16 * 64];

  const float* base = QKV + (size_t)b * NTOK * 2304;

  // Q fragments (held whole kernel), SCALE folded in: B[k=8lg+j] = Q[q=lr][dim]
  int qrow = qb * 64 + wq * 16 + lr;
  bfx8 qh[2], ql[2];
  {
    const float* qp = base + (size_t)qrow * 2304 + h * HEADD;
#pragma unroll
    for (int ks = 0; ks < 2; ks++) {
      float4 a0 = *(const float4*)(qp + ks * 32 + lg * 8);
      float4 a1 = *(const float4*)(qp + ks * 32 + lg * 8 + 4);
      float vv[8] = {a0.x, a0.y, a0.z, a0.w, a1.x, a1.y, a1.z, a1.w};
#pragma unroll
      for (int i = 0; i < 8; i++) {
        float sv = vv[i] * SCALE;
        __bf16 hh = (__bf16)sv;
        qh[ks][i] = hh;
        ql[ks][i] = (__bf16)(sv - (float)hh);
      }
    }
  }

  f32x4 oacc[4];
#pragma unroll
  for (int i = 0; i < 4; i++) oacc[i] = f32x4{0.f, 0.f, 0.f, 0.f};
  float mrun = -1e30f, l = 0.f;

  // staging thread roles
  int srow = tid >> 2, su = tid & 3;                       // K: key row, 16-dim slice
  const float* kgp = base + (size_t)srow * 2304 + CDIM + h * HEADD + su * 16;
  int vk = 4 * (tid & 15);                                 // V: 4-key x 4-dim micro-tile
  int vd = 4 * (tid >> 4);

  float4 kr[4];
  float vrf[4][4];
  {
    int k0 = kc * 512;
#pragma unroll
    for (int c = 0; c < 4; c++)
      kr[c] = *(const float4*)(kgp + (size_t)k0 * 2304 + c * 4);
#pragma unroll
    for (int i = 0; i < 4; i++) {
      float4 t = *(const float4*)(base + (size_t)(k0 + vk + i) * 2304 + 2 * CDIM + h * HEADD + vd);
      vrf[i][0] = t.x; vrf[i][1] = t.y; vrf[i][2] = t.z; vrf[i][3] = t.w;
    }
  }

  for (int t = 0; t < 8; t++) {
    __syncthreads();                    // all reads of previous tile done
    // ---- stage K (hi/lo, 72-elem padded rows)
    {
      int e = srow * 72 + su * 16;
#pragma unroll
      for (int c2 = 0; c2 < 2; c2++) {
        float vv[8] = {kr[2 * c2].x, kr[2 * c2].y, kr[2 * c2].z, kr[2 * c2].w,
                       kr[2 * c2 + 1].x, kr[2 * c2 + 1].y, kr[2 * c2 + 1].z, kr[2 * c2 + 1].w};
        u16x8 hv, lv;
#pragma unroll
        for (int i = 0; i < 8; i++) {
          unsigned short hu = f2bfu(vv[i]);
          hv[i] = hu;
          lv[i] = f2bfu(vv[i] - us2f(hu));
        }
        *(u16x8*)&KH[e + c2 * 8] = hv;
        *(u16x8*)&KL[e + c2 * 8] = lv;
      }
    }
    // ---- stage V TRANSPOSED: row d, keys vk..vk+3 as u16x4 (swizzled unit)
#pragma unroll
    for (int j = 0; j < 4; j++) {
      int d = vd + j;
      int off = d * 64 + (((vk >> 3) ^ (d & 7)) << 3) + (vk & 7);
      u16x4 hv, lv;
#pragma unroll
      for (int i = 0; i < 4; i++) {
        unsigned short hu = f2bfu(vrf[i][j]);
        hv[i] = hu;
        lv[i] = f2bfu(vrf[i][j] - us2f(hu));
      }
      *(u16x4*)&VTH[off] = hv;
      *(u16x4*)&VTL[off] = lv;
    }
    // ---- prefetch next tile (hides HBM under compute)
    if (t < 7) {
      int k0 = kc * 512 + (t + 1) * 64;
#pragma unroll
      for (int c = 0; c < 4; c++)
        kr[c] = *(const float4*)(kgp + (size_t)k0 * 2304 + c * 4);
#pragma unroll
      for (int i = 0; i < 4; i++) {
        float4 tv = *(const float4*)(base + (size_t)(k0 + vk + i) * 2304 + 2 * CDIM + h * HEADD + vd);
        vrf[i][0] = tv.x; vrf[i][1] = tv.y; vrf[i][2] = tv.z; vrf[i][3] = tv.w;
      }
    }
    __syncthreads();                    // staged tile visible

    // ---- S^T = K·Q^T (3 hi/lo products); sAcc[mf][r] = S[key=16mf+4lg+r][q=lr]
    f32x4 sAcc[4];
#pragma unroll
    for (int mf = 0; mf < 4; mf++) sAcc[mf] = f32x4{0.f, 0.f, 0.f, 0.f};
#pragma unroll
    for (int mf = 0; mf < 4; mf++) {
      int R = mf * 16 + lr;
#pragma unroll
      for (int ks = 0; ks < 2; ks++) {
        int e = R * 72 + (4 * ks + lg) * 8;
        bfx8 kh = *(const bfx8*)&KH[e];
        bfx8 kl = *(const bfx8*)&KL[e];
        sAcc[mf] = __builtin_amdgcn_mfma_f32_16x16x32_bf16(kh, qh[ks], sAcc[mf], 0, 0, 0);
        sAcc[mf] = __builtin_amdgcn_mfma_f32_16x16x32_bf16(kl, qh[ks], sAcc[mf], 0, 0, 0);
        sAcc[mf] = __builtin_amdgcn_mfma_f32_16x16x32_bf16(kh, ql[ks], sAcc[mf], 0, 0, 0);
      }
    }

    // ---- online softmax: lane owns q=lr, keys 16*mf + 4*lg + r
    float pmax = sAcc[0][0];
#pragma unroll
    for (int mf = 0; mf < 4; mf++)
#pragma unroll
      for (int r = 0; r < 4; r++) pmax = fmaxf(pmax, sAcc[mf][r]);
    pmax = fmaxf(pmax, __shfl_xor(pmax, 16, 64));
    pmax = fmaxf(pmax, __shfl_xor(pmax, 32, 64));
    if (!__all(pmax - mrun <= 8.f)) {       // defer-max THR=8 (p bounded by e^8)
      float mnew = fmaxf(mrun, pmax);
      float alpha = __expf(mrun - mnew);
      l *= alpha;
#pragma unroll
      for (int r = 0; r < 4; r++) {
        float ar = __shfl(alpha, 4 * lg + r, 64);   // alpha for acc row q=4lg+r
#pragma unroll
        for (int nf = 0; nf < 4; nf++) oacc[nf][r] *= ar;
      }
      mrun = mnew;
    }
    float p[4][4];
    float lsum = 0.f;
#pragma unroll
    for (int mf = 0; mf < 4; mf++)
#pragma unroll
      for (int r = 0; r < 4; r++) {
        float pv = __expf(sAcc[mf][r] - mrun);
        p[mf][r] = pv;
        lsum += pv;
      }
    lsum += __shfl_xor(lsum, 16, 64);
    lsum += __shfl_xor(lsum, 32, 64);
    l += lsum;

    // ---- P -> per-wave LDS: row q=lr, keys 16mf+4lg+(0..3) (u16x4, swizzled)
#pragma unroll
    for (int mf = 0; mf < 4; mf++) {
      int u = 2 * mf + (lg >> 1);
      int off = wq * 1024 + lr * 64 + ((u ^ (lr & 7)) << 3) + (lg & 1) * 4;
      u16x4 hv, lv;
#pragma unroll
      for (int r = 0; r < 4; r++) {
        unsigned short hu = f2bfu(p[mf][r]);
        hv[r] = hu;
        lv[r] = f2bfu(p[mf][r] - us2f(hu));
      }
      *(u16x4*)&PH[off] = hv;
      *(u16x4*)&PL_[off] = lv;
    }
    asm volatile("s_waitcnt lgkmcnt(0)" ::: "memory");   // per-wave P visibility
    __builtin_amdgcn_sched_barrier(0);

    // ---- O += P·V : A = P frags (natural key order), B = V^T frags (b128)
#pragma unroll
    for (int ks = 0; ks < 2; ks++) {
      int poff = wq * 1024 + lr * 64 + (((4 * ks + lg) ^ (lr & 7)) << 3);
      bfx8 pa_h = *(const bfx8*)&PH[poff];
      bfx8 pa_l = *(const bfx8*)&PL_[poff];
#pragma unroll
      for (int nf = 0; nf < 4; nf++) {
        int d = nf * 16 + lr;
        int voff = d * 64 + (((4 * ks + lg) ^ (d & 7)) << 3);
        bfx8 vb_h = *(const bfx8*)&VTH[voff];
        bfx8 vb_l = *(const bfx8*)&VTL[voff];
        oacc[nf] = __builtin_amdgcn_mfma_f32_16x16x32_bf16(pa_h, vb_h, oacc[nf], 0, 0, 0);
        oacc[nf] = __builtin_amdgcn_mfma_f32_16x16x32_bf16(pa_l, vb_h, oacc[nf], 0, 0, 0);
        oacc[nf] = __builtin_amdgcn_mfma_f32_16x16x32_bf16(pa_h, vb_l, oacc[nf], 0, 0, 0);
      }
    }
  }

  // ---- write partials (combine kernel unchanged)
  size_t idxbase = (size_t)(bh * 2 + kc) * NTOK;
  if (lane < 16) {
    PM[idxbase + qrow] = mrun;
    PL[idxbase + qrow] = l;
  }
#pragma unroll
  for (int r = 0; r < 4; r++) {
    int qg = qb * 64 + wq * 16 + 4 * lg + r;
    float* ap = PACC + (idxbase + qg) * 64;
#pragma unroll
    for (int nf = 0; nf < 4; nf++) ap[nf * 16 + lr] = oacc[nf][r];
  }
}

__global__ __launch_bounds__(256) void flash_combine(const float* __restrict__ PACC,
                                                     const float* __restrict__ PM,
                                                     const float* __restrict__ PL,
                                                     float* __restrict__ ATT) {
  int gid = blockIdx.x * 4 + (threadIdx.x >> 6);
  int lane = threadIdx.x & 63;
  int n = gid & (NTOK - 1);
  int bh = gid >> 10;
  size_t base = (size_t)bh * 2048 + n;
  float m0 = PM[base], m1 = PM[base + 1024];
  float mx = fmaxf(m0, m1);
  float w0 = __expf(m0 - mx), w1 = __expf(m1 - mx);
  float l = w0 * PL[base] + w1 * PL[base + 1024];
  float a = w0 * PACC[base * 64 + lane] + w1 * PACC[(base + 1024) * 64 + lane];
  int b = bh / NHEAD, h = bh - b * NHEAD;
  unsigned short* AHp = (unsigned short*)ATT;
  unsigned short* ALp = AHp + (size_t)ROWS * CDIM;
  stPlanes(a / l, ((size_t)(b * NTOK + n)) * CDIM + h * HEADD + lane, AHp, ALp);
}

// ---------------------------------------------------------------- output transpose (B,N,C)->(B,C,N)
__global__ __launch_bounds__(256) void out_kernel(const float* __restrict__ X,
                                                  void* __restrict__ out,
                                                  const int* __restrict__ dt) {
  bool isbf = (*dt != 0);
  int idx = blockIdx.x * 256 + threadIdx.x;
  int n = idx & (NTOK - 1);
  int rest = idx >> 10;
  int c = rest % CDIM;
  int b = rest / CDIM;
  float v = X[((size_t)(b * NTOK + n)) * CDIM + c];
  if (isbf)
    ((__hip_bfloat16*)out)[idx] = __float2bfloat16(v);
  else
    ((float*)out)[idx] = v;
}

// ---------------------------------------------------------------- launch
extern "C" void kernel_launch(void* const* d_in, const int* in_sizes, int n_in,
                              void* d_out, int out_size, void* d_ws, size_t ws_size,
                              hipStream_t stream) {
  const void* x       = d_in[0];
  const void* patch_w = d_in[1];
  const void* patch_b = d_in[2];
  const void* ln1_s   = d_in[3];
  const void* ln1_b   = d_in[4];
  const void* qkv_w   = d_in[5];
  const void* offs_w  = d_in[6];
  const void* offs_b  = d_in[7];
  const void* proj_w  = d_in[8];
  const void* proj_b  = d_in[9];
  const void* ln2_s   = d_in[10];
  const void* ln2_b   = d_in[11];
  const void* fc1_w   = d_in[12];
  const void* fc1_b   = d_in[13];
  const void* fc2_w   = d_in[14];
  const void* fc2_b   = d_in[15];

  float* W = (float*)d_ws;
  const size_t XSZ = (size_t)ROWS * CDIM;        // 1,572,864 floats
  float* X    = W;                               // residual stream (f32)
  float* Hb   = W + XSZ;                         // LN out (bf16 hi/lo planes)
  float* ATT  = W + 2 * XSZ;                     // attention out (planes)
  float* QKV  = W + 3 * XSZ;                     // 2048x2304 f32 (also im2col plane scratch)
  float* BIG  = W + 3 * XSZ + (size_t)ROWS * 2304;  // 2048x3072 (fc1 planes / flash PACC f32)
  float* OFFS = BIG + (size_t)ROWS * 3072;       // 2048x96 f32 (also flash PM/PL region)
  float* PM   = OFFS;
  float* PL   = OFFS + 24 * 4 * NTOK;
  float* Q    = OFFS + 196608;                   // q planes (XSZ floats region)
  int* FLAG   = (int*)(Q + XSZ);

  detect_kernel<<<1, 1, 0, stream>>>(qkv_w, FLAG);

  // patch embed: im2col (planes) -> GEMM
  im2col_kernel<<<6144, 256, 0, stream>>>(x, QKV, FLAG);
  gemm_kernel<<<dim3(12, 16), 256, 0, stream>>>((const unsigned short*)QKV, 768, patch_w, 0,
                                                patch_b, 0, X, 768, 768, 768, 0, FLAG);

  for (int i = 0; i < 6; i++) {
    ln_kernel<<<2048, 256, 0, stream>>>(X, ln1_s, ln1_b, (size_t)i * CDIM, Hb, FLAG);
    gemm_kernel<<<dim3(36, 16), 256, 0, stream>>>((const unsigned short*)Hb, 768, qkv_w,
                                                  (size_t)i * 2304 * 768,
                                                  nullptr, 0, QKV, 2304, 2304, 768, 0, FLAG);
    if ((i + 1) % 3 != 0) {
      cvtq_kernel<<<6144, 256, 0, stream>>>(QKV, Q);
      gemm_kernel<<<dim3(2, 16), 256, 0, stream>>>((const unsigned short*)Q, 768, offs_w,
                                                   (size_t)i * 96 * 768,
                                                   offs_b, (size_t)i * 96, OFFS, 96, 96, 768, 0, FLAG);
      deform_kernel<<<6144, 256, 0, stream>>>(QKV, OFFS, ATT);
    } else {
      flash_partial<<<768, 256, 0, stream>>>(QKV, BIG, PM, PL);
      flash_combine<<<6144, 256, 0, stream>>>(BIG, PM, PL, ATT);
    }
    gemm_kernel<<<dim3(12, 16), 256, 0, stream>>>((const unsigned short*)ATT, 768, proj_w,
                                                  (size_t)i * 768 * 768,
                                                  proj_b, (size_t)i * CDIM, X, 768, 768, 768, 1, FLAG);
    ln_kernel<<<2048, 256, 0, stream>>>(X, ln2_s, ln2_b, (size_t)i * CDIM, Hb, FLAG);
    gemm_kernel<<<dim3(48, 16), 256, 0, stream>>>((const unsigned short*)Hb, 768, fc1_w,
                                                  (size_t)i * 3072 * 768,
                                                  fc1_b, (size_t)i * 3072, BIG, 3072, 3072, 768, 6, FLAG);
    gemm_kernel<<<dim3(12, 16), 256, 0, stream>>>((const unsigned short*)BIG, 3072, fc2_w,
                                                  (size_t)i * 768 * 3072,
                                                  fc2_b, (size_t)i * CDIM, X, 768, 768, 3072, 1, FLAG);
  }

  out_kernel<<<6144, 256, 0, stream>>>(X, d_out, FLAG);
}

// Round 7
// 1568.005 us; speedup vs baseline: 4.0584x; 1.3171x over previous
//
#include <hip/hip_runtime.h>
#include <hip/hip_bf16.h>
#include <math.h>

// Problem constants
#define NTOK 1024          // Hp*Wp = 32*32
#define CDIM 768
#define BDIM 2
#define ROWS (BDIM*NTOK)   // 2048
#define NHEAD 12
#define HEADD 64
#define SCALE 0.125f       // 64^-0.5

typedef __attribute__((ext_vector_type(8))) __bf16 bfx8;
typedef __attribute__((ext_vector_type(4))) float f32x4;
typedef __attribute__((ext_vector_type(8))) unsigned short u16x8;
typedef __attribute__((ext_vector_type(4))) unsigned short u16x4;

__device__ __forceinline__ float us2f(unsigned short u) {
  return __uint_as_float(((unsigned int)u) << 16);
}
__device__ __forceinline__ unsigned short f2bfu(float v) {
  union { __bf16 b; unsigned short u; } c; c.b = (__bf16)v; return c.u;
}
// dtype-flexible scalar load at ELEMENT index i: isbf ? bf16[i] : f32[i]
__device__ __forceinline__ float ldP(const void* p, size_t i, bool isbf) {
  return isbf ? us2f(((const unsigned short*)p)[i]) : ((const float*)p)[i];
}
// split f32 -> bf16 hi + lo planes
__device__ __forceinline__ void stPlanes(float v, size_t idx,
                                         unsigned short* hp, unsigned short* lp) {
  unsigned short h = f2bfu(v);
  hp[idx] = h;
  lp[idx] = f2bfu(v - us2f(h));
}

__device__ __forceinline__ float waveSum(float v) {
#pragma unroll
  for (int off = 32; off; off >>= 1) v += __shfl_xor(v, off, 64);
  return v;
}

// ---------------------------------------------------------------- dtype detector
// bf16 buffer of 0.02-scale gaussians: ~256/256 halfwords have sane exponent.
// f32 buffer: only odd halfwords do (~152/256 expected). Threshold 220 (≈15σ).
__global__ void detect_kernel(const void* __restrict__ probe, int* __restrict__ flag) {
  const unsigned short* u = (const unsigned short*)probe;
  int plaus = 0;
  for (int i = 0; i < 256; i++) {
    int e = (u[i] >> 7) & 0xFF;
    if (e >= 0x60 && e <= 0x8F) plaus++;
  }
  *flag = (plaus >= 220) ? 1 : 0;
}

// ---------------------------------------------------------------- im2col (plane output)
__global__ __launch_bounds__(256) void im2col_kernel(const void* __restrict__ x,
                                                     float* __restrict__ col,
                                                     const int* __restrict__ dt) {
  bool isbf = (*dt != 0);
  int idx = blockIdx.x * 256 + threadIdx.x;     // < 2048*768
  int k = idx % 768;
  int row = idx / 768;
  int n = row & (NTOK - 1);
  int b = row >> 10;
  int ci = k >> 8;
  int rem = k & 255;
  int py = rem >> 4, px = rem & 15;
  int hp = n >> 5, wp = n & 31;
  int iy = hp * 16 + py, ix = wp * 16 + px;
  size_t xi = (((size_t)(b * 3 + ci) * 512) + iy) * 512 + ix;
  float v = ldP(x, xi, isbf);
  unsigned short* colH = (unsigned short*)col;
  unsigned short* colL = colH + (size_t)ROWS * CDIM;
  stPlanes(v, idx, colH, colL);
}

// ---------------------------------------------------------------- q columns -> planes
__global__ __launch_bounds__(256) void cvtq_kernel(const float* __restrict__ QKV,
                                                   float* __restrict__ Q) {
  int idx = blockIdx.x * 256 + threadIdx.x;     // < 2048*768
  int row = idx / 768, c = idx - row * 768;
  float v = QKV[(size_t)row * 2304 + c];
  unsigned short* qh = (unsigned short*)Q;
  unsigned short* ql = qh + (size_t)ROWS * CDIM;
  stPlanes(v, idx, qh, ql);
}

// ---------------------------------------------------------------- GEMM (MFMA, both dtypes)
// Y[m,n](ldy) (+)= A[m,k] @ W[wOff + n, k]^T + bias[bOff + n]
// A always given as bf16 hi/lo planes (AH base; AL = AH + ROWS*lda elems).
// isbf: W native bf16 -> 2 products. else: W f32, split in staging -> 3 products.
// Tile: M=128 x N=64, BK=32, 4 waves (each 32 rows x 64 cols).
// XCD-chunked bijective block swizzle (n-fastest): blocks sharing an A m-panel
// land on one XCD -> L2 reuse. Split-K via gridDim.z: each z computes K/gridDim.z
// and writes f32 partial to Ypart + z*ROWS*ldy (reduce_kernel combines).
// flags: bit0 residual add, bit1 exact GELU, bit2 plane output
__global__ __launch_bounds__(256) void gemm_kernel(
    const unsigned short* __restrict__ Aplanes, int lda,
    const void* __restrict__ Wraw, size_t wOff,
    const void* __restrict__ bias, size_t bOff,
    void* __restrict__ Yreg, int ldy,
    int Nout, int K, int flags, const int* __restrict__ dt,
    float* __restrict__ Ypart) {
  bool isbf = (*dt != 0);
  __shared__ __align__(16) unsigned char sm[24576];
  int tid = threadIdx.x;
  // XCD-chunked bijective swizzle (m204): same-chunk blocks share mbase
  int nwg = gridDim.x * gridDim.y;
  int orig = blockIdx.x + gridDim.x * blockIdx.y;
  int qq = nwg >> 3, rr = nwg & 7;
  int xcd = orig & 7, loc = orig >> 3;
  int wgid = (xcd < rr ? xcd * (qq + 1) : rr * (qq + 1) + (xcd - rr) * qq) + loc;
  int nbase = (wgid % gridDim.x) * 64;
  int mbase = (wgid / gridDim.x) * 128;
  // split-K range
  int KS = K / gridDim.z;
  int kb = blockIdx.z * KS;

  int lane = tid & 63, w = tid >> 6;
  int lr = lane & 15, lg = lane >> 4;

  const unsigned short* AH = Aplanes;
  const unsigned short* AL = AH + (size_t)ROWS * lda;

  int srow = tid >> 2;                               // staging row 0..63
  int swz = (tid & 3) ^ ((srow >> 1) & 3);           // swizzled 16B unit
  size_t gA0 = (size_t)(mbase + srow) * lda + swz * 8;
  size_t gA1 = gA0 + (size_t)64 * lda;
  int gn = nbase + srow; if (gn > Nout - 1) gn = Nout - 1;
  size_t gW = (size_t)gn * K + swz * 8;
  int wr0 = tid * 16;                                // LDS byte offsets (linear)
  int wr1 = wr0 + 4096;

  f32x4 acc[2][4];
#pragma unroll
  for (int i = 0; i < 2; i++)
#pragma unroll
    for (int j = 0; j < 4; j++) acc[i][j] = f32x4{0.f, 0.f, 0.f, 0.f};

  int ub = (lg ^ ((lr >> 1) & 3)) * 16;              // swizzled frag unit (bytes)
  int rmA = (w * 32 + lr) * 64;                      // byte row offset, mf=0

  if (isbf) {
    const unsigned short* Wb = (const unsigned short*)Wraw + wOff;
    u16x8 rA0h = *(const u16x8*)(AH + gA0 + kb);
    u16x8 rA1h = *(const u16x8*)(AH + gA1 + kb);
    u16x8 rA0l = *(const u16x8*)(AL + gA0 + kb);
    u16x8 rA1l = *(const u16x8*)(AL + gA1 + kb);
    u16x8 rW   = *(const u16x8*)(Wb + gW + kb);
    for (int k0 = kb; k0 < kb + KS; k0 += 32) {
      __syncthreads();
      *(u16x8*)(sm + wr0) = rA0h;
      *(u16x8*)(sm + wr1) = rA1h;
      *(u16x8*)(sm + 8192 + wr0) = rA0l;
      *(u16x8*)(sm + 8192 + wr1) = rA1l;
      *(u16x8*)(sm + 16384 + wr0) = rW;
      int k1 = k0 + 32;
      if (k1 < kb + KS) {                            // prefetch: hides under MFMA
        rA0h = *(const u16x8*)(AH + gA0 + k1);
        rA1h = *(const u16x8*)(AH + gA1 + k1);
        rA0l = *(const u16x8*)(AL + gA0 + k1);
        rA1l = *(const u16x8*)(AL + gA1 + k1);
        rW   = *(const u16x8*)(Wb + gW + k1);
      }
      __syncthreads();
      bfx8 ah0 = *(const bfx8*)(sm + rmA + ub);
      bfx8 ah1 = *(const bfx8*)(sm + rmA + 1024 + ub);
      bfx8 al0 = *(const bfx8*)(sm + 8192 + rmA + ub);
      bfx8 al1 = *(const bfx8*)(sm + 8192 + rmA + 1024 + ub);
#pragma unroll
      for (int nf = 0; nf < 4; nf++) {
        bfx8 wh = *(const bfx8*)(sm + 16384 + (nf * 16 + lr) * 64 + ub);
        acc[0][nf] = __builtin_amdgcn_mfma_f32_16x16x32_bf16(ah0, wh, acc[0][nf], 0, 0, 0);
        acc[0][nf] = __builtin_amdgcn_mfma_f32_16x16x32_bf16(al0, wh, acc[0][nf], 0, 0, 0);
        acc[1][nf] = __builtin_amdgcn_mfma_f32_16x16x32_bf16(ah1, wh, acc[1][nf], 0, 0, 0);
        acc[1][nf] = __builtin_amdgcn_mfma_f32_16x16x32_bf16(al1, wh, acc[1][nf], 0, 0, 0);
      }
    }
  } else {
    const float* Wf = (const float*)Wraw + wOff;
    u16x8 rA0h = *(const u16x8*)(AH + gA0 + kb);
    u16x8 rA1h = *(const u16x8*)(AH + gA1 + kb);
    u16x8 rA0l = *(const u16x8*)(AL + gA0 + kb);
    u16x8 rA1l = *(const u16x8*)(AL + gA1 + kb);
    float4 rW0 = *(const float4*)(Wf + gW + kb);
    float4 rW1 = *(const float4*)(Wf + gW + kb + 4);
    for (int k0 = kb; k0 < kb + KS; k0 += 32) {
      __syncthreads();
      *(u16x8*)(sm + wr0) = rA0h;
      *(u16x8*)(sm + wr1) = rA1h;
      *(u16x8*)(sm + 8192 + wr0) = rA0l;
      *(u16x8*)(sm + 8192 + wr1) = rA1l;
      {
        float wv[8] = {rW0.x, rW0.y, rW0.z, rW0.w, rW1.x, rW1.y, rW1.z, rW1.w};
        u16x8 wh8, wl8;
#pragma unroll
        for (int i = 0; i < 8; i++) {
          unsigned short h = f2bfu(wv[i]);
          wh8[i] = h;
          wl8[i] = f2bfu(wv[i] - us2f(h));
        }
        *(u16x8*)(sm + 16384 + wr0) = wh8;
        *(u16x8*)(sm + 20480 + wr0) = wl8;
      }
      int k1 = k0 + 32;
      if (k1 < kb + KS) {
        rA0h = *(const u16x8*)(AH + gA0 + k1);
        rA1h = *(const u16x8*)(AH + gA1 + k1);
        rA0l = *(const u16x8*)(AL + gA0 + k1);
        rA1l = *(const u16x8*)(AL + gA1 + k1);
        rW0  = *(const float4*)(Wf + gW + k1);
        rW1  = *(const float4*)(Wf + gW + k1 + 4);
      }
      __syncthreads();
      bfx8 ah0 = *(const bfx8*)(sm + rmA + ub);
      bfx8 ah1 = *(const bfx8*)(sm + rmA + 1024 + ub);
      bfx8 al0 = *(const bfx8*)(sm + 8192 + rmA + ub);
      bfx8 al1 = *(const bfx8*)(sm + 8192 + rmA + 1024 + ub);
#pragma unroll
      for (int nf = 0; nf < 4; nf++) {
        int rn = (nf * 16 + lr) * 64 + ub;
        bfx8 wh = *(const bfx8*)(sm + 16384 + rn);
        bfx8 wl = *(const bfx8*)(sm + 20480 + rn);
        acc[0][nf] = __builtin_amdgcn_mfma_f32_16x16x32_bf16(ah0, wh, acc[0][nf], 0, 0, 0);
        acc[0][nf] = __builtin_amdgcn_mfma_f32_16x16x32_bf16(al0, wh, acc[0][nf], 0, 0, 0);
        acc[0][nf] = __builtin_amdgcn_mfma_f32_16x16x32_bf16(ah0, wl, acc[0][nf], 0, 0, 0);
        acc[1][nf] = __builtin_amdgcn_mfma_f32_16x16x32_bf16(ah1, wh, acc[1][nf], 0, 0, 0);
        acc[1][nf] = __builtin_amdgcn_mfma_f32_16x16x32_bf16(al1, wh, acc[1][nf], 0, 0, 0);
        acc[1][nf] = __builtin_amdgcn_mfma_f32_16x16x32_bf16(ah1, wl, acc[1][nf], 0, 0, 0);
      }
    }
  }

  // ---- split-K partial epilogue: raw f32, no bias/act (reduce_kernel combines)
  if (gridDim.z > 1) {
    float* Pp = Ypart + (size_t)blockIdx.z * ((size_t)ROWS * ldy);
#pragma unroll
    for (int mf = 0; mf < 2; mf++)
#pragma unroll
      for (int nf = 0; nf < 4; nf++) {
        int n = nbase + nf * 16 + lr;
        if (n < Nout) {
#pragma unroll
          for (int r = 0; r < 4; r++) {
            int m = mbase + w * 32 + mf * 16 + lg * 4 + r;
            Pp[(size_t)m * ldy + n] = acc[mf][nf][r];
          }
        }
      }
    return;
  }

  // epilogue: D[row=(lane>>4)*4+r][col=lane&15] per 16x16 frag (verified layout)
  bool pOut = (flags & 4) != 0;
  unsigned short* YH = (unsigned short*)Yreg;
  unsigned short* YL = YH + (size_t)ROWS * ldy;
#pragma unroll
  for (int mf = 0; mf < 2; mf++) {
#pragma unroll
    for (int nf = 0; nf < 4; nf++) {
      int n = nbase + nf * 16 + lr;
      if (n < Nout) {
        float bv = bias ? ldP(bias, bOff + n, isbf) : 0.f;
#pragma unroll
        for (int r = 0; r < 4; r++) {
          int m = mbase + w * 32 + mf * 16 + lg * 4 + r;
          float v = acc[mf][nf][r] + bv;
          if (flags & 2) v = 0.5f * v * (1.0f + erff(v * 0.70710678118654752f));
          size_t yi = (size_t)m * ldy + n;
          if (pOut) {
            unsigned short h = f2bfu(v);
            YH[yi] = h;
            YL[yi] = f2bfu(v - us2f(h));
          } else {
            float* yp = (float*)Yreg + yi;
            if (flags & 1) v += *yp;
            *yp = v;
          }
        }
      }
    }
  }
}

// ---------------------------------------------------------------- split-K reduce
// X[idx] (+)= bias[bOff + idx%768] + sum_z PART[z*ROWS*768 + idx]
__global__ __launch_bounds__(256) void reduce_kernel(const float* __restrict__ PART,
                                                     int nsplit,
                                                     const void* __restrict__ bias,
                                                     size_t bOff,
                                                     float* __restrict__ X,
                                                     int resid,
                                                     const int* __restrict__ dt) {
  bool isbf = (*dt != 0);
  int idx = blockIdx.x * 256 + threadIdx.x;   // < 2048*768
  int n = idx % 768;
  float v = bias ? ldP(bias, bOff + n, isbf) : 0.f;
  const size_t XS = (size_t)ROWS * 768;
  for (int z = 0; z < nsplit; z++) v += PART[(size_t)z * XS + idx];
  X[idx] = resid ? (X[idx] + v) : v;
}

// ---------------------------------------------------------------- LayerNorm (plane output)
__global__ __launch_bounds__(256) void ln_kernel(const float* __restrict__ X,
                                                 const void* __restrict__ gs,
                                                 const void* __restrict__ gb,
                                                 size_t gOff,
                                                 float* __restrict__ H,
                                                 const int* __restrict__ dt) {
  bool isbf = (*dt != 0);
  int row = blockIdx.x;
  int tid = threadIdx.x;
  const float* xr = X + (size_t)row * CDIM;
  float v0 = xr[tid], v1 = xr[tid + 256], v2 = xr[tid + 512];
  float sum = waveSum(v0 + v1 + v2);
  __shared__ float red[4];
  __shared__ float statMu;
  __shared__ float statRs;
  int wid = tid >> 6, lane = tid & 63;
  if (lane == 0) red[wid] = sum;
  __syncthreads();
  if (tid == 0) statMu = (red[0] + red[1] + red[2] + red[3]) * (1.0f / 768.0f);
  __syncthreads();
  float mu = statMu;
  float d0 = v0 - mu, d1 = v1 - mu, d2 = v2 - mu;
  float sq = waveSum(d0 * d0 + d1 * d1 + d2 * d2);
  if (lane == 0) red[wid] = sq;
  __syncthreads();
  if (tid == 0)
    statRs = rsqrtf((red[0] + red[1] + red[2] + red[3]) * (1.0f / 768.0f) + 1e-6f);
  __syncthreads();
  float rs = statRs;
  unsigned short* HH = (unsigned short*)H;
  unsigned short* HL = HH + (size_t)ROWS * CDIM;
  size_t rb = (size_t)row * CDIM;
  float o0 = d0 * rs * ldP(gs, gOff + tid, isbf)       + ldP(gb, gOff + tid, isbf);
  float o1 = d1 * rs * ldP(gs, gOff + tid + 256, isbf) + ldP(gb, gOff + tid + 256, isbf);
  float o2 = d2 * rs * ldP(gs, gOff + tid + 512, isbf) + ldP(gb, gOff + tid + 512, isbf);
  stPlanes(o0, rb + tid, HH, HL);
  stPlanes(o1, rb + tid + 256, HH, HL);
  stPlanes(o2, rb + tid + 512, HH, HL);
}

// ---------------------------------------------------------------- deformable attention (plane output)
__global__ __launch_bounds__(256) void deform_kernel(const float* __restrict__ QKV,
                                                     const float* __restrict__ OFFS,
                                                     float* __restrict__ ATT) {
  int gid = blockIdx.x * 4 + (threadIdx.x >> 6);   // < 24576 = 2048*12
  int lane = threadIdx.x & 63;
  int h = gid % NHEAD;
  int bn = gid / NHEAD;          // b*1024 + n
  int n = bn & (NTOK - 1);
  int b = bn >> 10;
  int hp = n >> 5, wp = n & 31;

  float qd = QKV[(size_t)bn * 2304 + h * HEADD + lane];
  const float* orow = OFFS + (size_t)bn * 96 + h * 8;

  float sv[4], sc[4];
#pragma unroll
  for (int p = 0; p < 4; p++) {
    float ox = orow[p * 2 + 0];
    float oy = orow[p * 2 + 1];
    float xx = (float)wp + ox;
    float yy = (float)hp + oy;
    float x0f = floorf(xx), y0f = floorf(yy);
    int x0 = (int)x0f, y0 = (int)y0f;
    float wx = xx - x0f, wy = yy - y0f;
    int xs[2] = {x0, x0 + 1};
    int ys[2] = {y0, y0 + 1};
    float wxs[2] = {1.f - wx, wx};
    float wys[2] = {1.f - wy, wy};
    float skv = 0.f, svv = 0.f;
#pragma unroll
    for (int cy = 0; cy < 2; cy++) {
#pragma unroll
      for (int cx = 0; cx < 2; cx++) {
        int yi = ys[cy], xi = xs[cx];
        if (yi >= 0 && yi < 32 && xi >= 0 && xi < 32) {
          const float* kp = QKV + ((size_t)(b * NTOK + (yi << 5) + xi)) * 2304 + CDIM + h * HEADD + lane;
          float w = wys[cy] * wxs[cx];
          skv += w * kp[0];
          svv += w * kp[CDIM];
        }
      }
    }
    sv[p] = svv;
    sc[p] = waveSum(qd * skv) * SCALE;
  }
  float mx = fmaxf(fmaxf(sc[0], sc[1]), fmaxf(sc[2], sc[3]));
  float e0 = expf(sc[0] - mx), e1 = expf(sc[1] - mx), e2 = expf(sc[2] - mx), e3 = expf(sc[3] - mx);
  float l = e0 + e1 + e2 + e3;
  float od = (e0 * sv[0] + e1 * sv[1] + e2 * sv[2] + e3 * sv[3]) / l;
  unsigned short* AHp = (unsigned short*)ATT;
  unsigned short* ALp = AHp + (size_t)ROWS * CDIM;
  stPlanes(od, (size_t)bn * CDIM + h * HEADD + lane, AHp, ALp);
}

// ---------------------------------------------------------------- full attention (MFMA flash partial + combine)
// Per block: 64 queries (qb) x 512 keys (kc), 4 waves; wave owns 16 q, all keys.
// S^T = K·Q^T -> in-register online softmax -> P via per-wave LDS -> O += P·V
// (V staged transposed). All LDS 16B-unit XOR swizzled; hi/lo split everywhere.
__global__ __launch_bounds__(256) void flash_partial(const float* __restrict__ QKV,
                                                     float* __restrict__ PACC,
                                                     float* __restrict__ PM,
                                                     float* __restrict__ PL) {
  int bid = blockIdx.x;                 // ((b*12+h)*2 + kc)*16 + qb
  int qb = bid & 15;
  int kc = (bid >> 4) & 1;
  int bh = bid >> 5;                    // 0..23 = b*12 + h
  int h = bh % NHEAD;
  int b = bh / NHEAD;
  int tid = threadIdx.x;
  int lane = tid & 63, wq = tid >> 6;
  int lr = lane & 15, lg = lane >> 4;

  __shared__ __align__(16) unsigned short KH[64 * 72];   // K rows padded: 144B = 9x16B
  __shared__ __align__(16) unsigned short KL[64 * 72];
  __shared__ __align__(16) unsigned short VTH[64 * 64];  // V^T [d][key], swizzled units
  __shared__ __align__(16) unsigned short VTL[64 * 64];
  __shared__ __align__(16) unsigned short PH[4 * 16 * 64]; // per-wave P [q][key]
  __shared__ __align__(16) unsigned short PL_[4 * 16 * 64];

  const float* base = QKV + (size_t)b * NTOK * 2304;

  // Q fragments (held whole kernel), SCALE folded in: B[k=8lg+j] = Q[q=lr][dim]
  int qrow = qb * 64 + wq * 16 + lr;
  bfx8 qh[2], ql[2];
  {
    const float* qp = base + (size_t)qrow * 2304 + h * HEADD;
#pragma unroll
    for (int ks = 0; ks < 2; ks++) {
      float4 a0 = *(const float4*)(qp + ks * 32 + lg * 8);
      float4 a1 = *(const float4*)(qp + ks * 32 + lg * 8 + 4);
      float vv[8] = {a0.x, a0.y, a0.z, a0.w, a1.x, a1.y, a1.z, a1.w};
#pragma unroll
      for (int i = 0; i < 8; i++) {
        float sv = vv[i] * SCALE;
        __bf16 hh = (__bf16)sv;
        qh[ks][i] = hh;
        ql[ks][i] = (__bf16)(sv - (float)hh);
      }
    }
  }

  f32x4 oacc[4];
#pragma unroll
  for (int i = 0; i < 4; i++) oacc[i] = f32x4{0.f, 0.f, 0.f, 0.f};
  float mrun = -1e30f, l = 0.f;

  // staging thread roles
  int srow = tid >> 2, su = tid & 3;                       // K: key row, 16-dim slice
  const float* kgp = base + (size_t)srow * 2304 + CDIM + h * HEADD + su * 16;
  int vk = 4 * (tid & 15);                                 // V: 4-key x 4-dim micro-tile
  int vd = 4 * (tid >> 4);

  float4 kr[4];
  float vrf[4][4];
  {
    int k0 = kc * 512;
#pragma unroll
    for (int c = 0; c < 4; c++)
      kr[c] = *(const float4*)(kgp + (size_t)k0 * 2304 + c * 4);
#pragma unroll
    for (int i = 0; i < 4; i++) {
      float4 t = *(const float4*)(base + (size_t)(k0 + vk + i) * 2304 + 2 * CDIM + h * HEADD + vd);
      vrf[i][0] = t.x; vrf[i][1] = t.y; vrf[i][2] = t.z; vrf[i][3] = t.w;
    }
  }

  for (int t = 0; t < 8; t++) {
    __syncthreads();                    // all reads of previous tile done
    // ---- stage K (hi/lo, 72-elem padded rows)
    {
      int e = srow * 72 + su * 16;
#pragma unroll
      for (int c2 = 0; c2 < 2; c2++) {
        float vv[8] = {kr[2 * c2].x, kr[2 * c2].y, kr[2 * c2].z, kr[2 * c2].w,
                       kr[2 * c2 + 1].x, kr[2 * c2 + 1].y, kr[2 * c2 + 1].z, kr[2 * c2 + 1].w};
        u16x8 hv, lv;
#pragma unroll
        for (int i = 0; i < 8; i++) {
          unsigned short hu = f2bfu(vv[i]);
          hv[i] = hu;
          lv[i] = f2bfu(vv[i] - us2f(hu));
        }
        *(u16x8*)&KH[e + c2 * 8] = hv;
        *(u16x8*)&KL[e + c2 * 8] = lv;
      }
    }
    // ---- stage V TRANSPOSED: row d, keys vk..vk+3 as u16x4 (swizzled unit)
#pragma unroll
    for (int j = 0; j < 4; j++) {
      int d = vd + j;
      int off = d * 64 + (((vk >> 3) ^ (d & 7)) << 3) + (vk & 7);
      u16x4 hv, lv;
#pragma unroll
      for (int i = 0; i < 4; i++) {
        unsigned short hu = f2bfu(vrf[i][j]);
        hv[i] = hu;
        lv[i] = f2bfu(vrf[i][j] - us2f(hu));
      }
      *(u16x4*)&VTH[off] = hv;
      *(u16x4*)&VTL[off] = lv;
    }
    // ---- prefetch next tile (hides HBM under compute)
    if (t < 7) {
      int k0 = kc * 512 + (t + 1) * 64;
#pragma unroll
      for (int c = 0; c < 4; c++)
        kr[c] = *(const float4*)(kgp + (size_t)k0 * 2304 + c * 4);
#pragma unroll
      for (int i = 0; i < 4; i++) {
        float4 tv = *(const float4*)(base + (size_t)(k0 + vk + i) * 2304 + 2 * CDIM + h * HEADD + vd);
        vrf[i][0] = tv.x; vrf[i][1] = tv.y; vrf[i][2] = tv.z; vrf[i][3] = tv.w;
      }
    }
    __syncthreads();                    // staged tile visible

    // ---- S^T = K·Q^T (3 hi/lo products); sAcc[mf][r] = S[key=16mf+4lg+r][q=lr]
    f32x4 sAcc[4];
#pragma unroll
    for (int mf = 0; mf < 4; mf++) sAcc[mf] = f32x4{0.f, 0.f, 0.f, 0.f};
#pragma unroll
    for (int mf = 0; mf < 4; mf++) {
      int R = mf * 16 + lr;
#pragma unroll
      for (int ks = 0; ks < 2; ks++) {
        int e = R * 72 + (4 * ks + lg) * 8;
        bfx8 kh = *(const bfx8*)&KH[e];
        bfx8 kl = *(const bfx8*)&KL[e];
        sAcc[mf] = __builtin_amdgcn_mfma_f32_16x16x32_bf16(kh, qh[ks], sAcc[mf], 0, 0, 0);
        sAcc[mf] = __builtin_amdgcn_mfma_f32_16x16x32_bf16(kl, qh[ks], sAcc[mf], 0, 0, 0);
        sAcc[mf] = __builtin_amdgcn_mfma_f32_16x16x32_bf16(kh, ql[ks], sAcc[mf], 0, 0, 0);
      }
    }

    // ---- online softmax: lane owns q=lr, keys 16*mf + 4*lg + r
    float pmax = sAcc[0][0];
#pragma unroll
    for (int mf = 0; mf < 4; mf++)
#pragma unroll
      for (int r = 0; r < 4; r++) pmax = fmaxf(pmax, sAcc[mf][r]);
    pmax = fmaxf(pmax, __shfl_xor(pmax, 16, 64));
    pmax = fmaxf(pmax, __shfl_xor(pmax, 32, 64));
    if (!__all(pmax - mrun <= 8.f)) {       // defer-max THR=8 (p bounded by e^8)
      float mnew = fmaxf(mrun, pmax);
      float alpha = __expf(mrun - mnew);
      l *= alpha;
#pragma unroll
      for (int r = 0; r < 4; r++) {
        float ar = __shfl(alpha, 4 * lg + r, 64);   // alpha for acc row q=4lg+r
#pragma unroll
        for (int nf = 0; nf < 4; nf++) oacc[nf][r] *= ar;
      }
      mrun = mnew;
    }
    float p[4][4];
    float lsum = 0.f;
#pragma unroll
    for (int mf = 0; mf < 4; mf++)
#pragma unroll
      for (int r = 0; r < 4; r++) {
        float pv = __expf(sAcc[mf][r] - mrun);
        p[mf][r] = pv;
        lsum += pv;
      }
    lsum += __shfl_xor(lsum, 16, 64);
    lsum += __shfl_xor(lsum, 32, 64);
    l += lsum;

    // ---- P -> per-wave LDS: row q=lr, keys 16mf+4lg+(0..3) (u16x4, swizzled)
#pragma unroll
    for (int mf = 0; mf < 4; mf++) {
      int u = 2 * mf + (lg >> 1);
      int off = wq * 1024 + lr * 64 + ((u ^ (lr & 7)) << 3) + (lg & 1) * 4;
      u16x4 hv, lv;
#pragma unroll
      for (int r = 0; r < 4; r++) {
        unsigned short hu = f2bfu(p[mf][r]);
        hv[r] = hu;
        lv[r] = f2bfu(p[mf][r] - us2f(hu));
      }
      *(u16x4*)&PH[off] = hv;
      *(u16x4*)&PL_[off] = lv;
    }
    asm volatile("s_waitcnt lgkmcnt(0)" ::: "memory");   // per-wave P visibility
    __builtin_amdgcn_sched_barrier(0);

    // ---- O += P·V : A = P frags (natural key order), B = V^T frags (b128)
#pragma unroll
    for (int ks = 0; ks < 2; ks++) {
      int poff = wq * 1024 + lr * 64 + (((4 * ks + lg) ^ (lr & 7)) << 3);
      bfx8 pa_h = *(const bfx8*)&PH[poff];
      bfx8 pa_l = *(const bfx8*)&PL_[poff];
#pragma unroll
      for (int nf = 0; nf < 4; nf++) {
        int d = nf * 16 + lr;
        int voff = d * 64 + (((4 * ks + lg) ^ (d & 7)) << 3);
        bfx8 vb_h = *(const bfx8*)&VTH[voff];
        bfx8 vb_l = *(const bfx8*)&VTL[voff];
        oacc[nf] = __builtin_amdgcn_mfma_f32_16x16x32_bf16(pa_h, vb_h, oacc[nf], 0, 0, 0);
        oacc[nf] = __builtin_amdgcn_mfma_f32_16x16x32_bf16(pa_l, vb_h, oacc[nf], 0, 0, 0);
        oacc[nf] = __builtin_amdgcn_mfma_f32_16x16x32_bf16(pa_h, vb_l, oacc[nf], 0, 0, 0);
      }
    }
  }

  // ---- write partials (combine kernel unchanged)
  size_t idxbase = (size_t)(bh * 2 + kc) * NTOK;
  if (lane < 16) {
    PM[idxbase + qrow] = mrun;
    PL[idxbase + qrow] = l;
  }
#pragma unroll
  for (int r = 0; r < 4; r++) {
    int qg = qb * 64 + wq * 16 + 4 * lg + r;
    float* ap = PACC + (idxbase + qg) * 64;
#pragma unroll
    for (int nf = 0; nf < 4; nf++) ap[nf * 16 + lr] = oacc[nf][r];
  }
}

__global__ __launch_bounds__(256) void flash_combine(const float* __restrict__ PACC,
                                                     const float* __restrict__ PM,
                                                     const float* __restrict__ PL,
                                                     float* __restrict__ ATT) {
  int gid = blockIdx.x * 4 + (threadIdx.x >> 6);
  int lane = threadIdx.x & 63;
  int n = gid & (NTOK - 1);
  int bh = gid >> 10;
  size_t base = (size_t)bh * 2048 + n;
  float m0 = PM[base], m1 = PM[base + 1024];
  float mx = fmaxf(m0, m1);
  float w0 = __expf(m0 - mx), w1 = __expf(m1 - mx);
  float l = w0 * PL[base] + w1 * PL[base + 1024];
  float a = w0 * PACC[base * 64 + lane] + w1 * PACC[(base + 1024) * 64 + lane];
  int b = bh / NHEAD, h = bh - b * NHEAD;
  unsigned short* AHp = (unsigned short*)ATT;
  unsigned short* ALp = AHp + (size_t)ROWS * CDIM;
  stPlanes(a / l, ((size_t)(b * NTOK + n)) * CDIM + h * HEADD + lane, AHp, ALp);
}

// ---------------------------------------------------------------- output transpose (B,N,C)->(B,C,N)
__global__ __launch_bounds__(256) void out_kernel(const float* __restrict__ X,
                                                  void* __restrict__ out,
                                                  const int* __restrict__ dt) {
  bool isbf = (*dt != 0);
  int idx = blockIdx.x * 256 + threadIdx.x;
  int n = idx & (NTOK - 1);
  int rest = idx >> 10;
  int c = rest % CDIM;
  int b = rest / CDIM;
  float v = X[((size_t)(b * NTOK + n)) * CDIM + c];
  if (isbf)
    ((__hip_bfloat16*)out)[idx] = __float2bfloat16(v);
  else
    ((float*)out)[idx] = v;
}

// ---------------------------------------------------------------- launch
extern "C" void kernel_launch(void* const* d_in, const int* in_sizes, int n_in,
                              void* d_out, int out_size, void* d_ws, size_t ws_size,
                              hipStream_t stream) {
  const void* x       = d_in[0];
  const void* patch_w = d_in[1];
  const void* patch_b = d_in[2];
  const void* ln1_s   = d_in[3];
  const void* ln1_b   = d_in[4];
  const void* qkv_w   = d_in[5];
  const void* offs_w  = d_in[6];
  const void* offs_b  = d_in[7];
  const void* proj_w  = d_in[8];
  const void* proj_b  = d_in[9];
  const void* ln2_s   = d_in[10];
  const void* ln2_b   = d_in[11];
  const void* fc1_w   = d_in[12];
  const void* fc1_b   = d_in[13];
  const void* fc2_w   = d_in[14];
  const void* fc2_b   = d_in[15];

  float* W = (float*)d_ws;
  const size_t XSZ = (size_t)ROWS * CDIM;        // 1,572,864 floats
  float* X    = W;                               // residual stream (f32)
  float* Hb   = W + XSZ;                         // LN out (bf16 hi/lo planes)
  float* ATT  = W + 2 * XSZ;                     // attention out (planes)
  float* QKV  = W + 3 * XSZ;                     // 2048x2304 f32; dead after attn ->
                                                 //   reused as split-K partials (3*XSZ)
  float* BIG  = W + 3 * XSZ + (size_t)ROWS * 2304;  // 2048x3072 (fc1 planes / flash PACC
                                                 //   / patch split-K partials)
  float* OFFS = BIG + (size_t)ROWS * 3072;       // 2048x96 f32 (also flash PM/PL region)
  float* PM   = OFFS;
  float* PL   = OFFS + 24 * 4 * NTOK;
  float* Q    = OFFS + 196608;                   // q planes (XSZ floats region)
  int* FLAG   = (int*)(Q + XSZ);

  detect_kernel<<<1, 1, 0, stream>>>(qkv_w, FLAG);

  // patch embed: im2col (planes) -> GEMM
  im2col_kernel<<<6144, 256, 0, stream>>>(x, QKV, FLAG);
  gemm_kernel<<<dim3(12, 16), 256, 0, stream>>>((const unsigned short*)QKV, 768, patch_w, 0,
                                                patch_b, 0, X, 768, 768, 768, 0, FLAG, nullptr);

  for (int i = 0; i < 6; i++) {
    ln_kernel<<<2048, 256, 0, stream>>>(X, ln1_s, ln1_b, (size_t)i * CDIM, Hb, FLAG);
    gemm_kernel<<<dim3(36, 16), 256, 0, stream>>>((const unsigned short*)Hb, 768, qkv_w,
                                                  (size_t)i * 2304 * 768,
                                                  nullptr, 0, QKV, 2304, 2304, 768, 0, FLAG, nullptr);
    if ((i + 1) % 3 != 0) {
      cvtq_kernel<<<6144, 256, 0, stream>>>(QKV, Q);
      gemm_kernel<<<dim3(2, 16), 256, 0, stream>>>((const unsigned short*)Q, 768, offs_w,
                                                   (size_t)i * 96 * 768,
                                                   offs_b, (size_t)i * 96, OFFS, 96, 96, 768, 0, FLAG, nullptr);
      deform_kernel<<<6144, 256, 0, stream>>>(QKV, OFFS, ATT);
    } else {
      flash_partial<<<768, 256, 0, stream>>>(QKV, BIG, PM, PL);
      flash_combine<<<6144, 256, 0, stream>>>(BIG, PM, PL, ATT);
    }
    // proj: split-K=2 (QKV region is dead now -> partial buffers), reduce adds bias+residual
    gemm_kernel<<<dim3(12, 16, 2), 256, 0, stream>>>((const unsigned short*)ATT, 768, proj_w,
                                                     (size_t)i * 768 * 768,
                                                     nullptr, 0, X, 768, 768, 768, 0, FLAG, QKV);
    reduce_kernel<<<6144, 256, 0, stream>>>(QKV, 2, proj_b, (size_t)i * CDIM, X, 1, FLAG);
    ln_kernel<<<2048, 256, 0, stream>>>(X, ln2_s, ln2_b, (size_t)i * CDIM, Hb, FLAG);
    gemm_kernel<<<dim3(48, 16), 256, 0, stream>>>((const unsigned short*)Hb, 768, fc1_w,
                                                  (size_t)i * 3072 * 768,
                                                  fc1_b, (size_t)i * 3072, BIG, 3072, 3072, 768, 6, FLAG, nullptr);
    // fc2: split-K=3 into QKV region, reduce adds bias+residual
    gemm_kernel<<<dim3(12, 16, 3), 256, 0, stream>>>((const unsigned short*)BIG, 3072, fc2_w,
                                                     (size_t)i * 768 * 3072,
                                                     nullptr, 0, X, 768, 768, 3072, 0, FLAG, QKV);
    reduce_kernel<<<6144, 256, 0, stream>>>(QKV, 3, fc2_b, (size_t)i * CDIM, X, 1, FLAG);
  }

  out_kernel<<<6144, 256, 0, stream>>>(X, d_out, FLAG);
}